// Round 3
// baseline (335.727 us; speedup 1.0000x reference)
//
#include <hip/hip_runtime.h>
#include <hip/hip_bf16.h>
#include <stdint.h>

typedef __attribute__((ext_vector_type(8))) short s16x8;
typedef __attribute__((ext_vector_type(4))) float f32x4;
typedef __attribute__((ext_vector_type(4))) unsigned short u16x4;

#define D_MODEL 1024
#define D_INNER 2048
#define DT_RANK 64
#define NSTATE 16
#define BATCH 2
#define SEQ 2048
#define MROWS (BATCH*SEQ)   // 4096
#define NC 32
#define CLEN (SEQ/NC)       // 64

__device__ __forceinline__ float fsigmoid(float v) { return 1.f / (1.f + __expf(-v)); }

__device__ __forceinline__ unsigned short f2bf(float f) {
  __hip_bfloat16 h = __float2bfloat16(f);
  return *(unsigned short*)&h;
}

__device__ __forceinline__ float bf2f(unsigned short u) {
  return __uint_as_float(((unsigned int)u) << 16);
}

__device__ __forceinline__ void gl_lds16(const void* g, void* l) {
  __builtin_amdgcn_global_load_lds(
      (const __attribute__((address_space(1))) void*)g,
      (__attribute__((address_space(3))) void*)l, 16, 0, 0);
}

// ---------- setup: fp32->bf16 conversions + A = -exp(A_log), 8 elems/thread ----------
__global__ __launch_bounds__(256) void setup_convert(
    const float* __restrict__ x, const float* __restrict__ ipw,
    const float* __restrict__ xpw, const float* __restrict__ dtw,
    const float* __restrict__ opw, const float* __restrict__ alog,
    __hip_bfloat16* __restrict__ xbf, __hip_bfloat16* __restrict__ wbf,
    __hip_bfloat16* __restrict__ xpwbf, __hip_bfloat16* __restrict__ dtwbf,
    __hip_bfloat16* __restrict__ owbf, float* __restrict__ Aneg) {
  const int i = (blockIdx.x * 256 + threadIdx.x) * 8;
  const int n0 = MROWS * D_MODEL;               // x
  const int n1 = n0 + 2 * D_INNER * D_MODEL;    // in_proj
  const int n2 = n1 + 96 * D_INNER;             // x_proj
  const int n3 = n2 + D_INNER * DT_RANK;        // dt_proj
  const int n4 = n3 + D_MODEL * D_INNER;        // out_proj
  const int n5 = n4 + D_INNER * NSTATE;         // A_log
  const float* src; __hip_bfloat16* dst; int j;
  if (i < n0)      { src = x;    dst = xbf;   j = i; }
  else if (i < n1) { src = ipw;  dst = wbf;   j = i - n0; }
  else if (i < n2) { src = xpw;  dst = xpwbf; j = i - n1; }
  else if (i < n3) { src = dtw;  dst = dtwbf; j = i - n2; }
  else if (i < n4) { src = opw;  dst = owbf;  j = i - n3; }
  else if (i < n5) {
    int j2 = i - n4;
    float4 a = *(const float4*)(alog + j2);
    float4 b = *(const float4*)(alog + j2 + 4);
    float4 oa = {-expf(a.x), -expf(a.y), -expf(a.z), -expf(a.w)};
    float4 ob = {-expf(b.x), -expf(b.y), -expf(b.z), -expf(b.w)};
    *(float4*)(Aneg + j2) = oa;
    *(float4*)(Aneg + j2 + 4) = ob;
    return;
  } else return;
  float4 a = *(const float4*)(src + j);
  float4 b = *(const float4*)(src + j + 4);
  union { s16x8 v; unsigned short u[8]; } o;
  o.u[0] = f2bf(a.x); o.u[1] = f2bf(a.y); o.u[2] = f2bf(a.z); o.u[3] = f2bf(a.w);
  o.u[4] = f2bf(b.x); o.u[5] = f2bf(b.y); o.u[6] = f2bf(b.z); o.u[7] = f2bf(b.w);
  *(s16x8*)(dst + j) = o.v;
}

// ---------- m97-structure bf16 MFMA GEMM: C[M,N] = A[M,K] * Bw[N,K]^T ----------
// 128x128 tile, BK=32, global_load_lds width=16 into linear LDS (double-buffered),
// 4 waves 2x2, each wave 64x64 = 4x4 frags of 16x16x32.
// OPERAND-SWAPPED MFMA: mfma(b_frag, a_frag, acc) so each lane's 4 acc regs are
// 4 consecutive N-columns of one M-row -> vectorized 16B/8B epilogue stores.
// MODE 0: GEMM1 (in_proj): col<2048 -> xs bf16 (eb1); col>=2048 -> silu -> zsil bf16 (eb0)
// MODE 1: GEMM2 (x_proj, split-K): atomicAdd fp32 into xdbl[M][96]
// MODE 2: GEMM3 (dt_proj): +bias, softplus -> dt fp32
// MODE 3: GEMM4 (out_proj): plain fp32 store
template<int MODE>
__global__ __launch_bounds__(256)
void gemm_bt(const __hip_bfloat16* __restrict__ A,
             const __hip_bfloat16* __restrict__ Bw,
             int M, int N, int K, int kchunk,
             float* __restrict__ e0,
             __hip_bfloat16* __restrict__ eb0,
             __hip_bfloat16* __restrict__ eb1,
             const float* __restrict__ bias) {
  __shared__ unsigned short As[2 * 128 * 32];  // linear row*32+col per buffer (8KB each)
  __shared__ unsigned short Bs[2 * 128 * 32];
  const int m0 = blockIdx.x * 128;
  const int n0 = blockIdx.y * 128;
  const int kb = blockIdx.z * kchunk;
  const int nt = kchunk >> 5;
  const int tid = threadIdx.x;
  const int lane = tid & 63;
  const int wave = tid >> 6;
  const int wr = wave >> 1, wc = wave & 1;
  const int lrow = lane & 15;
  const int kh = lane >> 4;        // frag k-half: kh*8
  const int srow = lane >> 2;      // staging row within 16: 0..15
  const int sc8 = (lane & 3) * 8;  // staging col (elements)

  f32x4 acc[4][4] = {};

  auto STAGE = [&](int buf, int k0) {
#pragma unroll
    for (int i = 0; i < 2; ++i) {
      const int row = wave * 32 + i * 16 + srow;
      gl_lds16(A + (size_t)(m0 + row) * K + k0 + sc8,
               As + buf * 4096 + wave * 1024 + i * 512);
      int brow = n0 + row; if (brow >= N) brow = N - 1;
      gl_lds16(Bw + (size_t)brow * K + k0 + sc8,
               Bs + buf * 4096 + wave * 1024 + i * 512);
    }
  };

  STAGE(0, kb);
  __syncthreads();

  for (int t = 0; t < nt; ++t) {
    const int cur = t & 1;
    if (t + 1 < nt) STAGE(cur ^ 1, kb + ((t + 1) << 5));
    s16x8 af[4], bfr[4];
#pragma unroll
    for (int f = 0; f < 4; ++f)
      af[f] = *(const s16x8*)(As + cur * 4096 + (wr * 64 + f * 16 + lrow) * 32 + kh * 8);
#pragma unroll
    for (int g = 0; g < 4; ++g)
      bfr[g] = *(const s16x8*)(Bs + cur * 4096 + (wc * 64 + g * 16 + lrow) * 32 + kh * 8);
#pragma unroll
    for (int f = 0; f < 4; ++f)
#pragma unroll
      for (int g = 0; g < 4; ++g)
        acc[f][g] = __builtin_amdgcn_mfma_f32_16x16x32_bf16(bfr[g], af[f], acc[f][g], 0, 0, 0);
    if (t + 1 < nt) __syncthreads();
  }

  // epilogue (swapped D=C^T mapping): lane holds C[m][nb..nb+3],
  // m = frag m-base + (lane&15), nb = frag n-base + (lane>>4)*4
#pragma unroll
  for (int f = 0; f < 4; ++f) {
    const int m = m0 + wr * 64 + f * 16 + (lane & 15);
#pragma unroll
    for (int g = 0; g < 4; ++g) {
      const int nb = n0 + wc * 64 + g * 16 + (lane >> 4) * 4;
      f32x4 v = acc[f][g];
      if (MODE == 0) {
        if (nb < D_INNER) {
          u16x4 o = {f2bf(v[0]), f2bf(v[1]), f2bf(v[2]), f2bf(v[3])};
          *(u16x4*)((unsigned short*)eb1 + (size_t)m * D_INNER + nb) = o;
        } else {
          u16x4 o;
#pragma unroll
          for (int j = 0; j < 4; ++j) { float s = v[j] * fsigmoid(v[j]); o[j] = f2bf(s); }
          *(u16x4*)((unsigned short*)eb0 + (size_t)m * D_INNER + (nb - D_INNER)) = o;
        }
      } else if (MODE == 1) {
        if (nb < 96) {
#pragma unroll
          for (int j = 0; j < 4; ++j) atomicAdd(&e0[(size_t)m * 96 + nb + j], v[j]);
        }
      } else if (MODE == 2) {
        float4 bb = *(const float4*)(bias + nb);
        float4 r;
        float t0 = v[0] + bb.x; r.x = (t0 > 20.f) ? t0 : __logf(1.f + __expf(t0));
        float t1 = v[1] + bb.y; r.y = (t1 > 20.f) ? t1 : __logf(1.f + __expf(t1));
        float t2 = v[2] + bb.z; r.z = (t2 > 20.f) ? t2 : __logf(1.f + __expf(t2));
        float t3 = v[3] + bb.w; r.w = (t3 > 20.f) ? t3 : __logf(1.f + __expf(t3));
        *(float4*)(e0 + (size_t)m * D_INNER + nb) = r;
      } else {
        float4 r = {v[0], v[1], v[2], v[3]};
        *(float4*)(e0 + (size_t)m * D_MODEL + nb) = r;
      }
    }
  }
}

// ---------- split xdbl -> dt_r (bf16) + B/C (fp32) ----------
__global__ __launch_bounds__(256)
void xdbl_finish(const float* __restrict__ xdbl, __hip_bfloat16* __restrict__ dtrbf,
                 float* __restrict__ bc) {
  int i = blockIdx.x * 256 + threadIdx.x;  // 4096*96
  int r = i / 96, c = i - r * 96;
  float v = xdbl[i];
  if (c < DT_RANK) dtrbf[r * DT_RANK + c] = __float2bfloat16(v);
  else bc[r * 32 + (c - DT_RANK)] = v;
}

// ---------- depthwise causal conv (k=4) + bias + silu, 4 channels/thread, bf16 in ----------
__global__ __launch_bounds__(256)
void conv_silu(const __hip_bfloat16* __restrict__ xsb, const float* __restrict__ cw,
               const float* __restrict__ cb, float* __restrict__ xsc,
               __hip_bfloat16* __restrict__ xscbf) {
  const int g = blockIdx.x * 256 + threadIdx.x;  // 8388608/4 threads
  const int idx = g * 4;
  const int l = (idx >> 11) & (SEQ - 1);
  const int d = idx & (D_INNER - 1);
  const unsigned short* p = (const unsigned short*)xsb + idx;
  float4 xm3 = {0.f, 0.f, 0.f, 0.f}, xm2 = xm3, xm1 = xm3, x0;
  {
    u16x4 u = *(const u16x4*)(p);
    x0.x = bf2f(u[0]); x0.y = bf2f(u[1]); x0.z = bf2f(u[2]); x0.w = bf2f(u[3]);
  }
  if (l >= 1) { u16x4 u = *(const u16x4*)(p - 1 * D_INNER);
    xm1.x = bf2f(u[0]); xm1.y = bf2f(u[1]); xm1.z = bf2f(u[2]); xm1.w = bf2f(u[3]); }
  if (l >= 2) { u16x4 u = *(const u16x4*)(p - 2 * D_INNER);
    xm2.x = bf2f(u[0]); xm2.y = bf2f(u[1]); xm2.z = bf2f(u[2]); xm2.w = bf2f(u[3]); }
  if (l >= 3) { u16x4 u = *(const u16x4*)(p - 3 * D_INNER);
    xm3.x = bf2f(u[0]); xm3.y = bf2f(u[1]); xm3.z = bf2f(u[2]); xm3.w = bf2f(u[3]); }
  const float4* cwv = (const float4*)(cw + d * 4);
  float4 cb4 = *(const float4*)(cb + d);
  float4 out;
  { float4 q = cwv[0]; out.x = cb4.x + q.x * xm3.x + q.y * xm2.x + q.z * xm1.x + q.w * x0.x; }
  { float4 q = cwv[1]; out.y = cb4.y + q.x * xm3.y + q.y * xm2.y + q.z * xm1.y + q.w * x0.y; }
  { float4 q = cwv[2]; out.z = cb4.z + q.x * xm3.z + q.y * xm2.z + q.z * xm1.z + q.w * x0.z; }
  { float4 q = cwv[3]; out.w = cb4.w + q.x * xm3.w + q.y * xm2.w + q.z * xm1.w + q.w * x0.w; }
  out.x *= fsigmoid(out.x); out.y *= fsigmoid(out.y);
  out.z *= fsigmoid(out.z); out.w *= fsigmoid(out.w);
  *(float4*)(xsc + idx) = out;
  u16x4 ob = {f2bf(out.x), f2bf(out.y), f2bf(out.z), f2bf(out.w)};
  *(u16x4*)((unsigned short*)xscbf + idx) = ob;
}

// ---------- scan pass 1: per-chunk final state + decay product (h0=0) ----------
__global__ __launch_bounds__(256)
void scan_pass1(const float* __restrict__ dt, const float* __restrict__ xsc,
                const float* __restrict__ bc, const float* __restrict__ Aneg,
                float* __restrict__ hfin, float* __restrict__ Pbuf) {
  const int b = blockIdx.z, c = blockIdx.y;
  const int d = blockIdx.x * 256 + threadIdx.x;
  __shared__ float BC[CLEN][32];
  const size_t mrow0 = (size_t)b * SEQ + (size_t)c * CLEN;
  for (int t = threadIdx.x; t < CLEN * 32; t += 256) {
    int i = t >> 5, col = t & 31;
    BC[i][col] = bc[(mrow0 + i) * 32 + col];
  }
  __syncthreads();
  float Ar[16];
#pragma unroll
  for (int n = 0; n < 16; ++n) Ar[n] = Aneg[d * 16 + n];
  float h[16], P[16];
#pragma unroll
  for (int n = 0; n < 16; ++n) { h[n] = 0.f; P[n] = 1.f; }
  size_t base = mrow0 * D_INNER + d;
  for (int l = 0; l < CLEN; ++l) {
    float dtv = dt[base + (size_t)l * D_INNER];
    float u = dtv * xsc[base + (size_t)l * D_INNER];
#pragma unroll
    for (int n = 0; n < 16; ++n) {
      float a = __expf(dtv * Ar[n]);
      h[n] = h[n] * a + u * BC[l][n];
      P[n] *= a;
    }
  }
  size_t o = (((size_t)b * NC + c) * D_INNER + d) * 16;
#pragma unroll
  for (int n = 0; n < 16; ++n) { hfin[o + n] = h[n]; Pbuf[o + n] = P[n]; }
}

// ---------- scan pass 2: cross-chunk combine; hfin becomes h_init per chunk ----------
__global__ __launch_bounds__(256)
void scan_pass2(float* __restrict__ hfin, const float* __restrict__ Pbuf) {
  int idx = blockIdx.x * 256 + threadIdx.x;  // B*D_INNER*16 = 65536
  int b = idx >> 15;
  int dn = idx & 32767;
  float h0 = 0.f;
  for (int c = 0; c < NC; ++c) {
    size_t o = ((size_t)b * NC + c) * 32768 + dn;
    float hf = hfin[o], p = Pbuf[o];
    hfin[o] = h0;
    h0 = hf + p * h0;
  }
}

// ---------- scan pass 3: re-run chunk from h_init, emit y=(scan+xs*D)*silu(z) bf16 ----------
__global__ __launch_bounds__(256)
void scan_pass3(const float* __restrict__ dt, const float* __restrict__ xsc,
                const float* __restrict__ bc, const float* __restrict__ Aneg,
                const float* __restrict__ hinit, const float* __restrict__ Dv,
                const __hip_bfloat16* __restrict__ zsil,
                __hip_bfloat16* __restrict__ ybf) {
  const int b = blockIdx.z, c = blockIdx.y;
  const int d = blockIdx.x * 256 + threadIdx.x;
  __shared__ float BC[CLEN][32];
  const size_t mrow0 = (size_t)b * SEQ + (size_t)c * CLEN;
  for (int t = threadIdx.x; t < CLEN * 32; t += 256) {
    int i = t >> 5, col = t & 31;
    BC[i][col] = bc[(mrow0 + i) * 32 + col];
  }
  __syncthreads();
  float Ar[16];
#pragma unroll
  for (int n = 0; n < 16; ++n) Ar[n] = Aneg[d * 16 + n];
  float h[16];
  size_t o = (((size_t)b * NC + c) * D_INNER + d) * 16;
#pragma unroll
  for (int n = 0; n < 16; ++n) h[n] = hinit[o + n];
  const float dval = Dv[d];
  size_t base = mrow0 * D_INNER + d;
  for (int l = 0; l < CLEN; ++l) {
    float dtv = dt[base + (size_t)l * D_INNER];
    float xv = xsc[base + (size_t)l * D_INNER];
    float u = dtv * xv;
    float y = 0.f;
#pragma unroll
    for (int n = 0; n < 16; ++n) {
      float a = __expf(dtv * Ar[n]);
      h[n] = h[n] * a + u * BC[l][n];
      y += h[n] * BC[l][16 + n];
    }
    float yo = y + xv * dval;
    float zg = __bfloat162float(zsil[base + (size_t)l * D_INNER]);
    ybf[base + (size_t)l * D_INNER] = __float2bfloat16(yo * zg);
  }
}

extern "C" void kernel_launch(void* const* d_in, const int* in_sizes, int n_in,
                              void* d_out, int out_size, void* d_ws, size_t ws_size,
                              hipStream_t stream) {
  const float* x    = (const float*)d_in[0];
  const float* ipw  = (const float*)d_in[1];
  const float* cw   = (const float*)d_in[2];
  const float* cb   = (const float*)d_in[3];
  const float* xpw  = (const float*)d_in[4];
  const float* dtw  = (const float*)d_in[5];
  const float* dtb  = (const float*)d_in[6];
  const float* alog = (const float*)d_in[7];
  const float* Dv   = (const float*)d_in[8];
  const float* opw  = (const float*)d_in[9];
  float* out = (float*)d_out;

  char* w = (char*)d_ws;
  // layout (bytes); aliases: ybf over xbf+wbf (dead after GEMM1);
  // dtbuf over xsbf slot (xsbf dead after conv); xdbl over Pbuf (dead before scan1)
  __hip_bfloat16* xbf   = (__hip_bfloat16*)(w + 0);          //  8,388,608
  __hip_bfloat16* wbf   = (__hip_bfloat16*)(w + 8388608);    //  8,388,608
  __hip_bfloat16* ybf   = (__hip_bfloat16*)(w + 0);          // 16,777,216 (alias)
  __hip_bfloat16* owbf  = (__hip_bfloat16*)(w + 16777216);   //  4,194,304
  __hip_bfloat16* xpwbf = (__hip_bfloat16*)(w + 20971520);   //    393,216
  __hip_bfloat16* dtwbf = (__hip_bfloat16*)(w + 21364736);   //    262,144
  float* Aneg           = (float*)(w + 21626880);            //    131,072
  __hip_bfloat16* xsbf  = (__hip_bfloat16*)(w + 21757952);   // 16,777,216
  float* dtbuf          = (float*)(w + 21757952);            // 33,554,432 (alias)
  __hip_bfloat16* zsil  = (__hip_bfloat16*)(w + 55312384);   // 16,777,216
  float* xsc            = (float*)(w + 72089600);            // 33,554,432
  __hip_bfloat16* xscbf = (__hip_bfloat16*)(w + 105644032);  // 16,777,216
  __hip_bfloat16* dtrbf = (__hip_bfloat16*)(w + 122421248);  //    524,288
  float* bc             = (float*)(w + 122945536);           //    524,288
  float* hfin           = (float*)(w + 123469824);           //  8,388,608
  float* Pbuf           = (float*)(w + 131858432);           //  8,388,608
  float* xdbl           = (float*)(w + 131858432);           //  1,572,864 (alias of Pbuf)
  // total: 140,247,040 bytes

  // 1. convert inputs to bf16 (+ A = -exp(A_log))
  {
    const int total = MROWS * D_MODEL + 2 * D_INNER * D_MODEL + 96 * D_INNER +
                      D_INNER * DT_RANK + D_MODEL * D_INNER + D_INNER * NSTATE;
    setup_convert<<<total / (256 * 8), 256, 0, stream>>>(
        x, ipw, xpw, dtw, opw, alog, xbf, wbf, xpwbf, dtwbf, owbf, Aneg);
  }
  // 2. GEMM1: xz = x @ in_proj^T  -> xs bf16, silu(z) bf16
  gemm_bt<0><<<dim3(32, 32), 256, 0, stream>>>(xbf, wbf, MROWS, 2 * D_INNER, D_MODEL,
                                               D_MODEL, nullptr, zsil, xsbf, nullptr);
  // 3. depthwise conv + silu -> xsc fp32 + bf16
  conv_silu<<<(MROWS * D_INNER) / (256 * 4), 256, 0, stream>>>(xsbf, cw, cb, xsc, xscbf);
  // 4. GEMM2: x_dbl = xsc @ x_proj^T, split-K=16, atomicAdd -> xdbl fp32
  hipMemsetAsync(xdbl, 0, (size_t)MROWS * 96 * 4, stream);
  gemm_bt<1><<<dim3(32, 1, 16), 256, 0, stream>>>(xscbf, xpwbf, MROWS, 96, D_INNER,
                                                  D_INNER / 16, xdbl, nullptr, nullptr, nullptr);
  xdbl_finish<<<(MROWS * 96) / 256, 256, 0, stream>>>(xdbl, dtrbf, bc);
  // 5. GEMM3: dt = softplus(dt_r @ dt_proj^T + b) -> fp32
  gemm_bt<2><<<dim3(32, 16), 256, 0, stream>>>(dtrbf, dtwbf, MROWS, D_INNER, DT_RANK,
                                               DT_RANK, dtbuf, nullptr, nullptr, dtb);
  // 6-8. chunked selective scan
  scan_pass1<<<dim3(8, NC, 2), 256, 0, stream>>>(dtbuf, xsc, bc, Aneg, hfin, Pbuf);
  scan_pass2<<<256, 256, 0, stream>>>(hfin, Pbuf);
  scan_pass3<<<dim3(8, NC, 2), 256, 0, stream>>>(dtbuf, xsc, bc, Aneg, hfin, Dv, zsil, ybf);
  // 9. GEMM4: out = y @ out_proj^T
  gemm_bt<3><<<dim3(32, 8), 256, 0, stream>>>(ybf, owbf, MROWS, D_MODEL, D_INNER,
                                              D_INNER, out, nullptr, nullptr, nullptr);
}

// Round 4
// 252.229 us; speedup vs baseline: 1.3310x; 1.3310x over previous
//
#include <hip/hip_runtime.h>
#include <hip/hip_bf16.h>
#include <stdint.h>

typedef __attribute__((ext_vector_type(8))) short s16x8;
typedef __attribute__((ext_vector_type(4))) float f32x4;
typedef __attribute__((ext_vector_type(4))) unsigned short u16x4;

#define D_MODEL 1024
#define D_INNER 2048
#define DT_RANK 64
#define NSTATE 16
#define BATCH 2
#define SEQ 2048
#define MROWS (BATCH*SEQ)   // 4096
#define NC 32
#define CLEN (SEQ/NC)       // 64
#define KZ2 8               // GEMM2 split-K factor

__device__ __forceinline__ float fsigmoid(float v) { return 1.f / (1.f + __expf(-v)); }

__device__ __forceinline__ unsigned short f2bf(float f) {
  __hip_bfloat16 h = __float2bfloat16(f);
  return *(unsigned short*)&h;
}

__device__ __forceinline__ float bf2f(unsigned short u) {
  return __uint_as_float(((unsigned int)u) << 16);
}

__device__ __forceinline__ void gl_lds16(const void* g, void* l) {
  __builtin_amdgcn_global_load_lds(
      (const __attribute__((address_space(1))) void*)g,
      (__attribute__((address_space(3))) void*)l, 16, 0, 0);
}

// ---------- setup: fp32->bf16 conversions + A = -exp(A_log), 8 elems/thread ----------
__global__ __launch_bounds__(256) void setup_convert(
    const float* __restrict__ x, const float* __restrict__ ipw,
    const float* __restrict__ xpw, const float* __restrict__ dtw,
    const float* __restrict__ opw, const float* __restrict__ alog,
    __hip_bfloat16* __restrict__ xbf, __hip_bfloat16* __restrict__ wbf,
    __hip_bfloat16* __restrict__ xpwbf, __hip_bfloat16* __restrict__ dtwbf,
    __hip_bfloat16* __restrict__ owbf, float* __restrict__ Aneg) {
  const int i = (blockIdx.x * 256 + threadIdx.x) * 8;
  const int n0 = MROWS * D_MODEL;               // x
  const int n1 = n0 + 2 * D_INNER * D_MODEL;    // in_proj
  const int n2 = n1 + 96 * D_INNER;             // x_proj
  const int n3 = n2 + D_INNER * DT_RANK;        // dt_proj
  const int n4 = n3 + D_MODEL * D_INNER;        // out_proj
  const int n5 = n4 + D_INNER * NSTATE;         // A_log
  const float* src; __hip_bfloat16* dst; int j;
  if (i < n0)      { src = x;    dst = xbf;   j = i; }
  else if (i < n1) { src = ipw;  dst = wbf;   j = i - n0; }
  else if (i < n2) { src = xpw;  dst = xpwbf; j = i - n1; }
  else if (i < n3) { src = dtw;  dst = dtwbf; j = i - n2; }
  else if (i < n4) { src = opw;  dst = owbf;  j = i - n3; }
  else if (i < n5) {
    int j2 = i - n4;
    float4 a = *(const float4*)(alog + j2);
    float4 b = *(const float4*)(alog + j2 + 4);
    float4 oa = {-expf(a.x), -expf(a.y), -expf(a.z), -expf(a.w)};
    float4 ob = {-expf(b.x), -expf(b.y), -expf(b.z), -expf(b.w)};
    *(float4*)(Aneg + j2) = oa;
    *(float4*)(Aneg + j2 + 4) = ob;
    return;
  } else return;
  float4 a = *(const float4*)(src + j);
  float4 b = *(const float4*)(src + j + 4);
  union { s16x8 v; unsigned short u[8]; } o;
  o.u[0] = f2bf(a.x); o.u[1] = f2bf(a.y); o.u[2] = f2bf(a.z); o.u[3] = f2bf(a.w);
  o.u[4] = f2bf(b.x); o.u[5] = f2bf(b.y); o.u[6] = f2bf(b.z); o.u[7] = f2bf(b.w);
  *(s16x8*)(dst + j) = o.v;
}

// ---------- m97-structure bf16 MFMA GEMM: C[M,N] = A[M,K] * Bw[N,K]^T ----------
// 128x128 tile, BK=32, global_load_lds width=16 into linear LDS (double-buffered),
// 4 waves 2x2, operand-swapped MFMA -> lane holds C[m][nb..nb+3] (vectorized stores).
// MODE 0: GEMM1 (in_proj): col<2048 -> xs bf16 (eb1); col>=2048 -> silu -> zsil bf16 (eb0)
// MODE 1: GEMM2 (x_proj, split-K): fp32 partials, e0[(kz*M + m)*96 + nb]
// MODE 2: GEMM3 (dt_proj): +bias, softplus -> dt fp32
// MODE 3: GEMM4 (out_proj): plain fp32 store
template<int MODE>
__global__ __launch_bounds__(256)
void gemm_bt(const __hip_bfloat16* __restrict__ A,
             const __hip_bfloat16* __restrict__ Bw,
             int M, int N, int K, int kchunk,
             float* __restrict__ e0,
             __hip_bfloat16* __restrict__ eb0,
             __hip_bfloat16* __restrict__ eb1,
             const float* __restrict__ bias) {
  __shared__ unsigned short As[2 * 128 * 32];  // linear row*32+col per buffer (8KB each)
  __shared__ unsigned short Bs[2 * 128 * 32];
  const int m0 = blockIdx.x * 128;
  const int n0 = blockIdx.y * 128;
  const int kz = blockIdx.z;
  const int kb = kz * kchunk;
  const int nt = kchunk >> 5;
  const int tid = threadIdx.x;
  const int lane = tid & 63;
  const int wave = tid >> 6;
  const int wr = wave >> 1, wc = wave & 1;
  const int lrow = lane & 15;
  const int kh = lane >> 4;        // frag k-half: kh*8
  const int srow = lane >> 2;      // staging row within 16: 0..15
  const int sc8 = (lane & 3) * 8;  // staging col (elements)

  f32x4 acc[4][4] = {};

  auto STAGE = [&](int buf, int k0) {
#pragma unroll
    for (int i = 0; i < 2; ++i) {
      const int row = wave * 32 + i * 16 + srow;
      gl_lds16(A + (size_t)(m0 + row) * K + k0 + sc8,
               As + buf * 4096 + wave * 1024 + i * 512);
      int brow = n0 + row; if (brow >= N) brow = N - 1;
      gl_lds16(Bw + (size_t)brow * K + k0 + sc8,
               Bs + buf * 4096 + wave * 1024 + i * 512);
    }
  };

  STAGE(0, kb);
  __syncthreads();

  for (int t = 0; t < nt; ++t) {
    const int cur = t & 1;
    if (t + 1 < nt) STAGE(cur ^ 1, kb + ((t + 1) << 5));
    s16x8 af[4], bfr[4];
#pragma unroll
    for (int f = 0; f < 4; ++f)
      af[f] = *(const s16x8*)(As + cur * 4096 + (wr * 64 + f * 16 + lrow) * 32 + kh * 8);
#pragma unroll
    for (int g = 0; g < 4; ++g)
      bfr[g] = *(const s16x8*)(Bs + cur * 4096 + (wc * 64 + g * 16 + lrow) * 32 + kh * 8);
#pragma unroll
    for (int f = 0; f < 4; ++f)
#pragma unroll
      for (int g = 0; g < 4; ++g)
        acc[f][g] = __builtin_amdgcn_mfma_f32_16x16x32_bf16(bfr[g], af[f], acc[f][g], 0, 0, 0);
    if (t + 1 < nt) __syncthreads();
  }

  // epilogue (swapped D=C^T mapping): lane holds C[m][nb..nb+3]
#pragma unroll
  for (int f = 0; f < 4; ++f) {
    const int m = m0 + wr * 64 + f * 16 + (lane & 15);
#pragma unroll
    for (int g = 0; g < 4; ++g) {
      const int nb = n0 + wc * 64 + g * 16 + (lane >> 4) * 4;
      f32x4 v = acc[f][g];
      if (MODE == 0) {
        if (nb < D_INNER) {
          u16x4 o = {f2bf(v[0]), f2bf(v[1]), f2bf(v[2]), f2bf(v[3])};
          *(u16x4*)((unsigned short*)eb1 + (size_t)m * D_INNER + nb) = o;
        } else {
          u16x4 o;
#pragma unroll
          for (int j = 0; j < 4; ++j) { float s = v[j] * fsigmoid(v[j]); o[j] = f2bf(s); }
          *(u16x4*)((unsigned short*)eb0 + (size_t)m * D_INNER + (nb - D_INNER)) = o;
        }
      } else if (MODE == 1) {
        if (nb < 96) {
          float4 r = {v[0], v[1], v[2], v[3]};
          *(float4*)(e0 + ((size_t)kz * MROWS + m) * 96 + nb) = r;
        }
      } else if (MODE == 2) {
        float4 bb = *(const float4*)(bias + nb);
        float4 r;
        float t0 = v[0] + bb.x; r.x = (t0 > 20.f) ? t0 : __logf(1.f + __expf(t0));
        float t1 = v[1] + bb.y; r.y = (t1 > 20.f) ? t1 : __logf(1.f + __expf(t1));
        float t2 = v[2] + bb.z; r.z = (t2 > 20.f) ? t2 : __logf(1.f + __expf(t2));
        float t3 = v[3] + bb.w; r.w = (t3 > 20.f) ? t3 : __logf(1.f + __expf(t3));
        *(float4*)(e0 + (size_t)m * D_INNER + nb) = r;
      } else {
        float4 r = {v[0], v[1], v[2], v[3]};
        *(float4*)(e0 + (size_t)m * D_MODEL + nb) = r;
      }
    }
  }
}

// ---------- reduce 8 split-K partials -> dt_r (bf16) + B/C (fp32) ----------
__global__ __launch_bounds__(256)
void xdbl_finish(const float* __restrict__ xdbl8, __hip_bfloat16* __restrict__ dtrbf,
                 float* __restrict__ bc) {
  int i = blockIdx.x * 256 + threadIdx.x;  // 4096*96
  int r = i / 96, c = i - r * 96;
  float v = 0.f;
#pragma unroll
  for (int p = 0; p < KZ2; ++p) v += xdbl8[(size_t)p * (MROWS * 96) + i];
  if (c < DT_RANK) dtrbf[r * DT_RANK + c] = __float2bfloat16(v);
  else bc[r * 32 + (c - DT_RANK)] = v;
}

// ---------- depthwise causal conv (k=4) + bias + silu, 4 channels/thread, bf16 in/out ----------
__global__ __launch_bounds__(256)
void conv_silu(const __hip_bfloat16* __restrict__ xsb, const float* __restrict__ cw,
               const float* __restrict__ cb,
               __hip_bfloat16* __restrict__ xscbf) {
  const int g = blockIdx.x * 256 + threadIdx.x;  // 8388608/4 threads
  const int idx = g * 4;
  const int l = (idx >> 11) & (SEQ - 1);
  const int d = idx & (D_INNER - 1);
  const unsigned short* p = (const unsigned short*)xsb + idx;
  float4 xm3 = {0.f, 0.f, 0.f, 0.f}, xm2 = xm3, xm1 = xm3, x0;
  {
    u16x4 u = *(const u16x4*)(p);
    x0.x = bf2f(u[0]); x0.y = bf2f(u[1]); x0.z = bf2f(u[2]); x0.w = bf2f(u[3]);
  }
  if (l >= 1) { u16x4 u = *(const u16x4*)(p - 1 * D_INNER);
    xm1.x = bf2f(u[0]); xm1.y = bf2f(u[1]); xm1.z = bf2f(u[2]); xm1.w = bf2f(u[3]); }
  if (l >= 2) { u16x4 u = *(const u16x4*)(p - 2 * D_INNER);
    xm2.x = bf2f(u[0]); xm2.y = bf2f(u[1]); xm2.z = bf2f(u[2]); xm2.w = bf2f(u[3]); }
  if (l >= 3) { u16x4 u = *(const u16x4*)(p - 3 * D_INNER);
    xm3.x = bf2f(u[0]); xm3.y = bf2f(u[1]); xm3.z = bf2f(u[2]); xm3.w = bf2f(u[3]); }
  const float4* cwv = (const float4*)(cw + d * 4);
  float4 cb4 = *(const float4*)(cb + d);
  float4 out;
  { float4 q = cwv[0]; out.x = cb4.x + q.x * xm3.x + q.y * xm2.x + q.z * xm1.x + q.w * x0.x; }
  { float4 q = cwv[1]; out.y = cb4.y + q.x * xm3.y + q.y * xm2.y + q.z * xm1.y + q.w * x0.y; }
  { float4 q = cwv[2]; out.z = cb4.z + q.x * xm3.z + q.y * xm2.z + q.z * xm1.z + q.w * x0.z; }
  { float4 q = cwv[3]; out.w = cb4.w + q.x * xm3.w + q.y * xm2.w + q.z * xm1.w + q.w * x0.w; }
  out.x *= fsigmoid(out.x); out.y *= fsigmoid(out.y);
  out.z *= fsigmoid(out.z); out.w *= fsigmoid(out.w);
  u16x4 ob = {f2bf(out.x), f2bf(out.y), f2bf(out.z), f2bf(out.w)};
  *(u16x4*)((unsigned short*)xscbf + idx) = ob;
}

// ---------- scan pass 1: per-chunk final state + decay product (h0=0) ----------
__global__ __launch_bounds__(256)
void scan_pass1(const float* __restrict__ dt, const __hip_bfloat16* __restrict__ xsc,
                const float* __restrict__ bc, const float* __restrict__ Aneg,
                float* __restrict__ hfin, float* __restrict__ Pbuf) {
  const int b = blockIdx.z, c = blockIdx.y;
  const int d = blockIdx.x * 256 + threadIdx.x;
  __shared__ float BC[CLEN][32];
  const size_t mrow0 = (size_t)b * SEQ + (size_t)c * CLEN;
  for (int t = threadIdx.x; t < CLEN * 32; t += 256) {
    int i = t >> 5, col = t & 31;
    BC[i][col] = bc[(mrow0 + i) * 32 + col];
  }
  __syncthreads();
  float Ar[16];
#pragma unroll
  for (int n = 0; n < 16; ++n) Ar[n] = Aneg[d * 16 + n];
  float h[16], P[16];
#pragma unroll
  for (int n = 0; n < 16; ++n) { h[n] = 0.f; P[n] = 1.f; }
  size_t base = mrow0 * D_INNER + d;
  for (int l = 0; l < CLEN; ++l) {
    float dtv = dt[base + (size_t)l * D_INNER];
    float u = dtv * bf2f(((const unsigned short*)xsc)[base + (size_t)l * D_INNER]);
#pragma unroll
    for (int n = 0; n < 16; ++n) {
      float a = __expf(dtv * Ar[n]);
      h[n] = h[n] * a + u * BC[l][n];
      P[n] *= a;
    }
  }
  size_t o = (((size_t)b * NC + c) * D_INNER + d) * 16;
#pragma unroll
  for (int n = 0; n < 16; ++n) { hfin[o + n] = h[n]; Pbuf[o + n] = P[n]; }
}

// ---------- scan pass 2: cross-chunk combine; hfin becomes h_init per chunk ----------
__global__ __launch_bounds__(256)
void scan_pass2(float* __restrict__ hfin, const float* __restrict__ Pbuf) {
  int idx = blockIdx.x * 256 + threadIdx.x;  // B*D_INNER*16 = 65536
  int b = idx >> 15;
  int dn = idx & 32767;
  float h0 = 0.f;
  for (int c = 0; c < NC; ++c) {
    size_t o = ((size_t)b * NC + c) * 32768 + dn;
    float hf = hfin[o], p = Pbuf[o];
    hfin[o] = h0;
    h0 = hf + p * h0;
  }
}

// ---------- scan pass 3: re-run chunk from h_init, emit y=(scan+xs*D)*silu(z) bf16 ----------
__global__ __launch_bounds__(256)
void scan_pass3(const float* __restrict__ dt, const __hip_bfloat16* __restrict__ xsc,
                const float* __restrict__ bc, const float* __restrict__ Aneg,
                const float* __restrict__ hinit, const float* __restrict__ Dv,
                const __hip_bfloat16* __restrict__ zsil,
                __hip_bfloat16* __restrict__ ybf) {
  const int b = blockIdx.z, c = blockIdx.y;
  const int d = blockIdx.x * 256 + threadIdx.x;
  __shared__ float BC[CLEN][32];
  const size_t mrow0 = (size_t)b * SEQ + (size_t)c * CLEN;
  for (int t = threadIdx.x; t < CLEN * 32; t += 256) {
    int i = t >> 5, col = t & 31;
    BC[i][col] = bc[(mrow0 + i) * 32 + col];
  }
  __syncthreads();
  float Ar[16];
#pragma unroll
  for (int n = 0; n < 16; ++n) Ar[n] = Aneg[d * 16 + n];
  float h[16];
  size_t o = (((size_t)b * NC + c) * D_INNER + d) * 16;
#pragma unroll
  for (int n = 0; n < 16; ++n) h[n] = hinit[o + n];
  const float dval = Dv[d];
  size_t base = mrow0 * D_INNER + d;
  for (int l = 0; l < CLEN; ++l) {
    float dtv = dt[base + (size_t)l * D_INNER];
    float xv = bf2f(((const unsigned short*)xsc)[base + (size_t)l * D_INNER]);
    float u = dtv * xv;
    float y = 0.f;
#pragma unroll
    for (int n = 0; n < 16; ++n) {
      float a = __expf(dtv * Ar[n]);
      h[n] = h[n] * a + u * BC[l][n];
      y += h[n] * BC[l][16 + n];
    }
    float yo = y + xv * dval;
    float zg = __bfloat162float(zsil[base + (size_t)l * D_INNER]);
    ybf[base + (size_t)l * D_INNER] = __float2bfloat16(yo * zg);
  }
}

extern "C" void kernel_launch(void* const* d_in, const int* in_sizes, int n_in,
                              void* d_out, int out_size, void* d_ws, size_t ws_size,
                              hipStream_t stream) {
  const float* x    = (const float*)d_in[0];
  const float* ipw  = (const float*)d_in[1];
  const float* cw   = (const float*)d_in[2];
  const float* cb   = (const float*)d_in[3];
  const float* xpw  = (const float*)d_in[4];
  const float* dtw  = (const float*)d_in[5];
  const float* dtb  = (const float*)d_in[6];
  const float* alog = (const float*)d_in[7];
  const float* Dv   = (const float*)d_in[8];
  const float* opw  = (const float*)d_in[9];
  float* out = (float*)d_out;

  char* w = (char*)d_ws;
  // layout (bytes); aliases: ybf over xbf+wbf (dead after GEMM1);
  // dtbuf over xsbf slot (xsbf dead after conv); xdbl8 over hfin+Pbuf (dead before scan1)
  __hip_bfloat16* xbf   = (__hip_bfloat16*)(w + 0);          //  8,388,608
  __hip_bfloat16* wbf   = (__hip_bfloat16*)(w + 8388608);    //  8,388,608
  __hip_bfloat16* ybf   = (__hip_bfloat16*)(w + 0);          // 16,777,216 (alias)
  __hip_bfloat16* owbf  = (__hip_bfloat16*)(w + 16777216);   //  4,194,304
  __hip_bfloat16* xpwbf = (__hip_bfloat16*)(w + 20971520);   //    393,216
  __hip_bfloat16* dtwbf = (__hip_bfloat16*)(w + 21364736);   //    262,144
  float* Aneg           = (float*)(w + 21626880);            //    131,072
  __hip_bfloat16* xsbf  = (__hip_bfloat16*)(w + 21757952);   // 16,777,216
  float* dtbuf          = (float*)(w + 21757952);            // 33,554,432 (alias)
  __hip_bfloat16* zsil  = (__hip_bfloat16*)(w + 55312384);   // 16,777,216
  __hip_bfloat16* xscbf = (__hip_bfloat16*)(w + 105644032);  // 16,777,216
  __hip_bfloat16* dtrbf = (__hip_bfloat16*)(w + 122421248);  //    524,288
  float* bc             = (float*)(w + 122945536);           //    524,288
  float* hfin           = (float*)(w + 123469824);           //  8,388,608
  float* Pbuf           = (float*)(w + 131858432);           //  8,388,608
  float* xdbl8          = (float*)(w + 123469824);           // 12,582,912 (alias hfin+Pbuf)
  // total: 140,247,040 bytes

  // 1. convert inputs to bf16 (+ A = -exp(A_log))
  {
    const int total = MROWS * D_MODEL + 2 * D_INNER * D_MODEL + 96 * D_INNER +
                      D_INNER * DT_RANK + D_MODEL * D_INNER + D_INNER * NSTATE;
    setup_convert<<<total / (256 * 8), 256, 0, stream>>>(
        x, ipw, xpw, dtw, opw, alog, xbf, wbf, xpwbf, dtwbf, owbf, Aneg);
  }
  // 2. GEMM1: xz = x @ in_proj^T  -> xs bf16, silu(z) bf16
  gemm_bt<0><<<dim3(32, 32), 256, 0, stream>>>(xbf, wbf, MROWS, 2 * D_INNER, D_MODEL,
                                               D_MODEL, nullptr, zsil, xsbf, nullptr);
  // 3. depthwise conv + silu -> xsc bf16
  conv_silu<<<(MROWS * D_INNER) / (256 * 4), 256, 0, stream>>>(xsbf, cw, cb, xscbf);
  // 4. GEMM2: x_dbl = xsc @ x_proj^T, split-K=8 partials (no atomics) + reduce
  gemm_bt<1><<<dim3(32, 1, KZ2), 256, 0, stream>>>(xscbf, xpwbf, MROWS, 96, D_INNER,
                                                   D_INNER / KZ2, xdbl8, nullptr, nullptr, nullptr);
  xdbl_finish<<<(MROWS * 96) / 256, 256, 0, stream>>>(xdbl8, dtrbf, bc);
  // 5. GEMM3: dt = softplus(dt_r @ dt_proj^T + b) -> fp32
  gemm_bt<2><<<dim3(32, 16), 256, 0, stream>>>(dtrbf, dtwbf, MROWS, D_INNER, DT_RANK,
                                               DT_RANK, dtbuf, nullptr, nullptr, dtb);
  // 6-8. chunked selective scan
  scan_pass1<<<dim3(8, NC, 2), 256, 0, stream>>>(dtbuf, xscbf, bc, Aneg, hfin, Pbuf);
  scan_pass2<<<256, 256, 0, stream>>>(hfin, Pbuf);
  scan_pass3<<<dim3(8, NC, 2), 256, 0, stream>>>(dtbuf, xscbf, bc, Aneg, hfin, Dv, zsil, ybf);
  // 9. GEMM4: out = y @ out_proj^T
  gemm_bt<3><<<dim3(32, 8), 256, 0, stream>>>(ybf, owbf, MROWS, D_MODEL, D_INNER,
                                              D_INNER, out, nullptr, nullptr, nullptr);
}

// Round 5
// 246.041 us; speedup vs baseline: 1.3645x; 1.0251x over previous
//
#include <hip/hip_runtime.h>
#include <hip/hip_bf16.h>
#include <hip/hip_fp16.h>
#include <stdint.h>

typedef __attribute__((ext_vector_type(8))) short s16x8;
typedef __attribute__((ext_vector_type(4))) float f32x4;
typedef __attribute__((ext_vector_type(4))) unsigned short u16x4;

#define D_MODEL 1024
#define D_INNER 2048
#define DT_RANK 64
#define NSTATE 16
#define BATCH 2
#define SEQ 2048
#define MROWS (BATCH*SEQ)   // 4096
#define NC 32
#define CLEN (SEQ/NC)       // 64
#define KZ2 8               // GEMM2 split-K factor

__device__ __forceinline__ float fsigmoid(float v) { return 1.f / (1.f + __expf(-v)); }

__device__ __forceinline__ unsigned short f2bf(float f) {
  __hip_bfloat16 h = __float2bfloat16(f);
  return *(unsigned short*)&h;
}

__device__ __forceinline__ float bf2f(unsigned short u) {
  return __uint_as_float(((unsigned int)u) << 16);
}

__device__ __forceinline__ void gl_lds16(const void* g, void* l) {
  __builtin_amdgcn_global_load_lds(
      (const __attribute__((address_space(1))) void*)g,
      (__attribute__((address_space(3))) void*)l, 16, 0, 0);
}

// ---------- setup: fp32->bf16 conversions + A = -exp(A_log), 8 elems/thread ----------
__global__ __launch_bounds__(256) void setup_convert(
    const float* __restrict__ x, const float* __restrict__ ipw,
    const float* __restrict__ xpw, const float* __restrict__ dtw,
    const float* __restrict__ opw, const float* __restrict__ alog,
    __hip_bfloat16* __restrict__ xbf, __hip_bfloat16* __restrict__ wbf,
    __hip_bfloat16* __restrict__ xpwbf, __hip_bfloat16* __restrict__ dtwbf,
    __hip_bfloat16* __restrict__ owbf, float* __restrict__ Aneg) {
  const int i = (blockIdx.x * 256 + threadIdx.x) * 8;
  const int n0 = MROWS * D_MODEL;               // x
  const int n1 = n0 + 2 * D_INNER * D_MODEL;    // in_proj
  const int n2 = n1 + 96 * D_INNER;             // x_proj
  const int n3 = n2 + D_INNER * DT_RANK;        // dt_proj
  const int n4 = n3 + D_MODEL * D_INNER;        // out_proj
  const int n5 = n4 + D_INNER * NSTATE;         // A_log
  const float* src; __hip_bfloat16* dst; int j;
  if (i < n0)      { src = x;    dst = xbf;   j = i; }
  else if (i < n1) { src = ipw;  dst = wbf;   j = i - n0; }
  else if (i < n2) { src = xpw;  dst = xpwbf; j = i - n1; }
  else if (i < n3) { src = dtw;  dst = dtwbf; j = i - n2; }
  else if (i < n4) { src = opw;  dst = owbf;  j = i - n3; }
  else if (i < n5) {
    int j2 = i - n4;
    float4 a = *(const float4*)(alog + j2);
    float4 b = *(const float4*)(alog + j2 + 4);
    float4 oa = {-expf(a.x), -expf(a.y), -expf(a.z), -expf(a.w)};
    float4 ob = {-expf(b.x), -expf(b.y), -expf(b.z), -expf(b.w)};
    *(float4*)(Aneg + j2) = oa;
    *(float4*)(Aneg + j2 + 4) = ob;
    return;
  } else return;
  float4 a = *(const float4*)(src + j);
  float4 b = *(const float4*)(src + j + 4);
  union { s16x8 v; unsigned short u[8]; } o;
  o.u[0] = f2bf(a.x); o.u[1] = f2bf(a.y); o.u[2] = f2bf(a.z); o.u[3] = f2bf(a.w);
  o.u[4] = f2bf(b.x); o.u[5] = f2bf(b.y); o.u[6] = f2bf(b.z); o.u[7] = f2bf(b.w);
  *(s16x8*)(dst + j) = o.v;
}

// ---------- m97-structure bf16 MFMA GEMM: C[M,N] = A[M,K] * Bw[N,K]^T ----------
// BM x 128 tile (BM=128 or 64), BK=32, global_load_lds width=16 into linear LDS
// (double-buffered), 4 waves 2x2, operand-swapped MFMA -> lane holds C[m][nb..nb+3].
// BM=64 doubles grid for occupancy-starved shapes (GEMM2/3/4).
// MODE 0: GEMM1 (in_proj): col<2048 -> xs bf16 (eb1); col>=2048 -> silu -> zsil bf16 (eb0)
// MODE 1: GEMM2 (x_proj, split-K): fp32 partials, e0[(kz*M + m)*96 + nb]
// MODE 2: GEMM3 (dt_proj): +bias, softplus -> dt fp16 (eh)
// MODE 3: GEMM4 (out_proj): plain fp32 store
template<int MODE, int BM>
__global__ __launch_bounds__(256)
void gemm_bt(const __hip_bfloat16* __restrict__ A,
             const __hip_bfloat16* __restrict__ Bw,
             int M, int N, int K, int kchunk,
             float* __restrict__ e0,
             __hip_bfloat16* __restrict__ eb0,
             __hip_bfloat16* __restrict__ eb1,
             __half* __restrict__ eh,
             const float* __restrict__ bias) {
  constexpr int FM = BM / 32;       // M-frags per wave (4 or 2)
  constexpr int ABUF = BM * 32;     // shorts per A buffer
  constexpr int AW = ABUF / 4;      // shorts per wave per A buffer
  constexpr int AI = BM / 64;       // A staging gl_lds per thread (2 or 1)
  __shared__ unsigned short As[2 * ABUF];
  __shared__ unsigned short Bs[2 * 128 * 32];
  const int m0 = blockIdx.x * BM;
  const int n0 = blockIdx.y * 128;
  const int kz = blockIdx.z;
  const int kb = kz * kchunk;
  const int nt = kchunk >> 5;
  const int tid = threadIdx.x;
  const int lane = tid & 63;
  const int wave = tid >> 6;
  const int wr = wave >> 1, wc = wave & 1;
  const int lrow = lane & 15;
  const int kh = lane >> 4;        // frag k-half: kh*8
  const int srow = lane >> 2;      // staging row within 16: 0..15
  const int sc8 = (lane & 3) * 8;  // staging col (elements)

  f32x4 acc[FM][4] = {};

  auto STAGE = [&](int buf, int k0) {
#pragma unroll
    for (int i = 0; i < AI; ++i) {
      const int row = wave * (AW / 32) + i * 16 + srow;
      gl_lds16(A + (size_t)(m0 + row) * K + k0 + sc8,
               As + buf * ABUF + wave * AW + i * 512);
    }
#pragma unroll
    for (int i = 0; i < 2; ++i) {
      const int row = wave * 32 + i * 16 + srow;
      int brow = n0 + row; if (brow >= N) brow = N - 1;
      gl_lds16(Bw + (size_t)brow * K + k0 + sc8,
               Bs + buf * 4096 + wave * 1024 + i * 512);
    }
  };

  STAGE(0, kb);
  __syncthreads();

  for (int t = 0; t < nt; ++t) {
    const int cur = t & 1;
    if (t + 1 < nt) STAGE(cur ^ 1, kb + ((t + 1) << 5));
    s16x8 af[FM], bfr[4];
#pragma unroll
    for (int f = 0; f < FM; ++f)
      af[f] = *(const s16x8*)(As + cur * ABUF + (wr * (BM / 2) + f * 16 + lrow) * 32 + kh * 8);
#pragma unroll
    for (int g = 0; g < 4; ++g)
      bfr[g] = *(const s16x8*)(Bs + cur * 4096 + (wc * 64 + g * 16 + lrow) * 32 + kh * 8);
#pragma unroll
    for (int f = 0; f < FM; ++f)
#pragma unroll
      for (int g = 0; g < 4; ++g)
        acc[f][g] = __builtin_amdgcn_mfma_f32_16x16x32_bf16(bfr[g], af[f], acc[f][g], 0, 0, 0);
    if (t + 1 < nt) __syncthreads();
  }

  // epilogue (swapped D=C^T mapping): lane holds C[m][nb..nb+3]
#pragma unroll
  for (int f = 0; f < FM; ++f) {
    const int m = m0 + wr * (BM / 2) + f * 16 + (lane & 15);
#pragma unroll
    for (int g = 0; g < 4; ++g) {
      const int nb = n0 + wc * 64 + g * 16 + (lane >> 4) * 4;
      f32x4 v = acc[f][g];
      if (MODE == 0) {
        if (nb < D_INNER) {
          u16x4 o = {f2bf(v[0]), f2bf(v[1]), f2bf(v[2]), f2bf(v[3])};
          *(u16x4*)((unsigned short*)eb1 + (size_t)m * D_INNER + nb) = o;
        } else {
          u16x4 o;
#pragma unroll
          for (int j = 0; j < 4; ++j) { float s = v[j] * fsigmoid(v[j]); o[j] = f2bf(s); }
          *(u16x4*)((unsigned short*)eb0 + (size_t)m * D_INNER + (nb - D_INNER)) = o;
        }
      } else if (MODE == 1) {
        if (nb < 96) {
          float4 r = {v[0], v[1], v[2], v[3]};
          *(float4*)(e0 + ((size_t)kz * MROWS + m) * 96 + nb) = r;
        }
      } else if (MODE == 2) {
        float4 bb = *(const float4*)(bias + nb);
        u16x4 o;
        float t0 = v[0] + bb.x; float r0 = (t0 > 20.f) ? t0 : __logf(1.f + __expf(t0));
        float t1 = v[1] + bb.y; float r1 = (t1 > 20.f) ? t1 : __logf(1.f + __expf(t1));
        float t2 = v[2] + bb.z; float r2 = (t2 > 20.f) ? t2 : __logf(1.f + __expf(t2));
        float t3 = v[3] + bb.w; float r3 = (t3 > 20.f) ? t3 : __logf(1.f + __expf(t3));
        o[0] = __half_as_ushort(__float2half(r0));
        o[1] = __half_as_ushort(__float2half(r1));
        o[2] = __half_as_ushort(__float2half(r2));
        o[3] = __half_as_ushort(__float2half(r3));
        *(u16x4*)((unsigned short*)eh + (size_t)m * D_INNER + nb) = o;
      } else {
        float4 r = {v[0], v[1], v[2], v[3]};
        *(float4*)(e0 + (size_t)m * D_MODEL + nb) = r;
      }
    }
  }
}

// ---------- reduce 8 split-K partials -> dt_r (bf16) + B/C (fp32) ----------
__global__ __launch_bounds__(256)
void xdbl_finish(const float* __restrict__ xdbl8, __hip_bfloat16* __restrict__ dtrbf,
                 float* __restrict__ bc) {
  int i = blockIdx.x * 256 + threadIdx.x;  // 4096*96
  int r = i / 96, c = i - r * 96;
  float v = 0.f;
#pragma unroll
  for (int p = 0; p < KZ2; ++p) v += xdbl8[(size_t)p * (MROWS * 96) + i];
  if (c < DT_RANK) dtrbf[r * DT_RANK + c] = __float2bfloat16(v);
  else bc[r * 32 + (c - DT_RANK)] = v;
}

// ---------- depthwise causal conv (k=4) + bias + silu, 4 channels/thread, bf16 in/out ----------
__global__ __launch_bounds__(256)
void conv_silu(const __hip_bfloat16* __restrict__ xsb, const float* __restrict__ cw,
               const float* __restrict__ cb,
               __hip_bfloat16* __restrict__ xscbf) {
  const int g = blockIdx.x * 256 + threadIdx.x;  // 8388608/4 threads
  const int idx = g * 4;
  const int l = (idx >> 11) & (SEQ - 1);
  const int d = idx & (D_INNER - 1);
  const unsigned short* p = (const unsigned short*)xsb + idx;
  float4 xm3 = {0.f, 0.f, 0.f, 0.f}, xm2 = xm3, xm1 = xm3, x0;
  {
    u16x4 u = *(const u16x4*)(p);
    x0.x = bf2f(u[0]); x0.y = bf2f(u[1]); x0.z = bf2f(u[2]); x0.w = bf2f(u[3]);
  }
  if (l >= 1) { u16x4 u = *(const u16x4*)(p - 1 * D_INNER);
    xm1.x = bf2f(u[0]); xm1.y = bf2f(u[1]); xm1.z = bf2f(u[2]); xm1.w = bf2f(u[3]); }
  if (l >= 2) { u16x4 u = *(const u16x4*)(p - 2 * D_INNER);
    xm2.x = bf2f(u[0]); xm2.y = bf2f(u[1]); xm2.z = bf2f(u[2]); xm2.w = bf2f(u[3]); }
  if (l >= 3) { u16x4 u = *(const u16x4*)(p - 3 * D_INNER);
    xm3.x = bf2f(u[0]); xm3.y = bf2f(u[1]); xm3.z = bf2f(u[2]); xm3.w = bf2f(u[3]); }
  const float4* cwv = (const float4*)(cw + d * 4);
  float4 cb4 = *(const float4*)(cb + d);
  float4 out;
  { float4 q = cwv[0]; out.x = cb4.x + q.x * xm3.x + q.y * xm2.x + q.z * xm1.x + q.w * x0.x; }
  { float4 q = cwv[1]; out.y = cb4.y + q.x * xm3.y + q.y * xm2.y + q.z * xm1.y + q.w * x0.y; }
  { float4 q = cwv[2]; out.z = cb4.z + q.x * xm3.z + q.y * xm2.z + q.z * xm1.z + q.w * x0.z; }
  { float4 q = cwv[3]; out.w = cb4.w + q.x * xm3.w + q.y * xm2.w + q.z * xm1.w + q.w * x0.w; }
  out.x *= fsigmoid(out.x); out.y *= fsigmoid(out.y);
  out.z *= fsigmoid(out.z); out.w *= fsigmoid(out.w);
  u16x4 ob = {f2bf(out.x), f2bf(out.y), f2bf(out.z), f2bf(out.w)};
  *(u16x4*)((unsigned short*)xscbf + idx) = ob;
}

// ---------- scan pass 1: per-chunk final state + decay product (h0=0) ----------
// P[n] = prod_l exp(dt_l*A[n]) = exp(A[n] * sum_l dt_l)  -> track dtsum only
__global__ __launch_bounds__(256)
void scan_pass1(const __half* __restrict__ dt, const __hip_bfloat16* __restrict__ xsc,
                const float* __restrict__ bc, const float* __restrict__ Aneg,
                float* __restrict__ hfin, float* __restrict__ Pbuf) {
  const int b = blockIdx.z, c = blockIdx.y;
  const int d = blockIdx.x * 256 + threadIdx.x;
  __shared__ float BC[CLEN][32];
  const size_t mrow0 = (size_t)b * SEQ + (size_t)c * CLEN;
  for (int t = threadIdx.x; t < CLEN * 32; t += 256) {
    int i = t >> 5, col = t & 31;
    BC[i][col] = bc[(mrow0 + i) * 32 + col];
  }
  __syncthreads();
  float Ar[16];
#pragma unroll
  for (int n = 0; n < 16; ++n) Ar[n] = Aneg[d * 16 + n];
  float h[16];
#pragma unroll
  for (int n = 0; n < 16; ++n) h[n] = 0.f;
  float dtsum = 0.f;
  size_t base = mrow0 * D_INNER + d;
  for (int l = 0; l < CLEN; ++l) {
    float dtv = __half2float(dt[base + (size_t)l * D_INNER]);
    float u = dtv * bf2f(((const unsigned short*)xsc)[base + (size_t)l * D_INNER]);
    dtsum += dtv;
#pragma unroll
    for (int n = 0; n < 16; ++n) {
      float a = __expf(dtv * Ar[n]);
      h[n] = h[n] * a + u * BC[l][n];
    }
  }
  size_t o = (((size_t)b * NC + c) * D_INNER + d) * 16;
#pragma unroll
  for (int n = 0; n < 16; ++n) { hfin[o + n] = h[n]; Pbuf[o + n] = __expf(dtsum * Ar[n]); }
}

// ---------- scan pass 2: cross-chunk combine; hfin becomes h_init per chunk ----------
__global__ __launch_bounds__(256)
void scan_pass2(float* __restrict__ hfin, const float* __restrict__ Pbuf) {
  int idx = blockIdx.x * 256 + threadIdx.x;  // B*D_INNER*16 = 65536
  int b = idx >> 15;
  int dn = idx & 32767;
  float h0 = 0.f;
  for (int c = 0; c < NC; ++c) {
    size_t o = ((size_t)b * NC + c) * 32768 + dn;
    float hf = hfin[o], p = Pbuf[o];
    hfin[o] = h0;
    h0 = hf + p * h0;
  }
}

// ---------- scan pass 3: re-run chunk from h_init, emit y=(scan+xs*D)*silu(z) bf16 ----------
__global__ __launch_bounds__(256)
void scan_pass3(const __half* __restrict__ dt, const __hip_bfloat16* __restrict__ xsc,
                const float* __restrict__ bc, const float* __restrict__ Aneg,
                const float* __restrict__ hinit, const float* __restrict__ Dv,
                const __hip_bfloat16* __restrict__ zsil,
                __hip_bfloat16* __restrict__ ybf) {
  const int b = blockIdx.z, c = blockIdx.y;
  const int d = blockIdx.x * 256 + threadIdx.x;
  __shared__ float BC[CLEN][32];
  const size_t mrow0 = (size_t)b * SEQ + (size_t)c * CLEN;
  for (int t = threadIdx.x; t < CLEN * 32; t += 256) {
    int i = t >> 5, col = t & 31;
    BC[i][col] = bc[(mrow0 + i) * 32 + col];
  }
  __syncthreads();
  float Ar[16];
#pragma unroll
  for (int n = 0; n < 16; ++n) Ar[n] = Aneg[d * 16 + n];
  float h[16];
  size_t o = (((size_t)b * NC + c) * D_INNER + d) * 16;
#pragma unroll
  for (int n = 0; n < 16; ++n) h[n] = hinit[o + n];
  const float dval = Dv[d];
  size_t base = mrow0 * D_INNER + d;
  for (int l = 0; l < CLEN; ++l) {
    float dtv = __half2float(dt[base + (size_t)l * D_INNER]);
    float xv = bf2f(((const unsigned short*)xsc)[base + (size_t)l * D_INNER]);
    float u = dtv * xv;
    float y = 0.f;
#pragma unroll
    for (int n = 0; n < 16; ++n) {
      float a = __expf(dtv * Ar[n]);
      h[n] = h[n] * a + u * BC[l][n];
      y += h[n] * BC[l][16 + n];
    }
    float yo = y + xv * dval;
    float zg = __bfloat162float(zsil[base + (size_t)l * D_INNER]);
    ybf[base + (size_t)l * D_INNER] = __float2bfloat16(yo * zg);
  }
}

extern "C" void kernel_launch(void* const* d_in, const int* in_sizes, int n_in,
                              void* d_out, int out_size, void* d_ws, size_t ws_size,
                              hipStream_t stream) {
  const float* x    = (const float*)d_in[0];
  const float* ipw  = (const float*)d_in[1];
  const float* cw   = (const float*)d_in[2];
  const float* cb   = (const float*)d_in[3];
  const float* xpw  = (const float*)d_in[4];
  const float* dtw  = (const float*)d_in[5];
  const float* dtb  = (const float*)d_in[6];
  const float* alog = (const float*)d_in[7];
  const float* Dv   = (const float*)d_in[8];
  const float* opw  = (const float*)d_in[9];
  float* out = (float*)d_out;

  char* w = (char*)d_ws;
  // layout (bytes); aliases: ybf over xbf+wbf (dead after GEMM1);
  // dtbuf (fp16) over xsbf slot (xsbf dead after conv); xdbl8 over hfin+Pbuf
  __hip_bfloat16* xbf   = (__hip_bfloat16*)(w + 0);          //  8,388,608
  __hip_bfloat16* wbf   = (__hip_bfloat16*)(w + 8388608);    //  8,388,608
  __hip_bfloat16* ybf   = (__hip_bfloat16*)(w + 0);          // 16,777,216 (alias)
  __hip_bfloat16* owbf  = (__hip_bfloat16*)(w + 16777216);   //  4,194,304
  __hip_bfloat16* xpwbf = (__hip_bfloat16*)(w + 20971520);   //    393,216
  __hip_bfloat16* dtwbf = (__hip_bfloat16*)(w + 21364736);   //    262,144
  float* Aneg           = (float*)(w + 21626880);            //    131,072
  __hip_bfloat16* xsbf  = (__hip_bfloat16*)(w + 21757952);   // 16,777,216
  __half* dtbuf         = (__half*)(w + 21757952);           // 16,777,216 (alias)
  __hip_bfloat16* zsil  = (__hip_bfloat16*)(w + 55312384);   // 16,777,216
  __hip_bfloat16* xscbf = (__hip_bfloat16*)(w + 105644032);  // 16,777,216
  __hip_bfloat16* dtrbf = (__hip_bfloat16*)(w + 122421248);  //    524,288
  float* bc             = (float*)(w + 122945536);           //    524,288
  float* hfin           = (float*)(w + 123469824);           //  8,388,608
  float* Pbuf           = (float*)(w + 131858432);           //  8,388,608
  float* xdbl8          = (float*)(w + 123469824);           // 12,582,912 (alias hfin+Pbuf)
  // total: 140,247,040 bytes

  // 1. convert inputs to bf16 (+ A = -exp(A_log))
  {
    const int total = MROWS * D_MODEL + 2 * D_INNER * D_MODEL + 96 * D_INNER +
                      D_INNER * DT_RANK + D_MODEL * D_INNER + D_INNER * NSTATE;
    setup_convert<<<total / (256 * 8), 256, 0, stream>>>(
        x, ipw, xpw, dtw, opw, alog, xbf, wbf, xpwbf, dtwbf, owbf, Aneg);
  }
  // 2. GEMM1: xz = x @ in_proj^T  -> xs bf16, silu(z) bf16   (128x128 tiles, 1024 blocks)
  gemm_bt<0, 128><<<dim3(32, 32), 256, 0, stream>>>(
      xbf, wbf, MROWS, 2 * D_INNER, D_MODEL, D_MODEL,
      nullptr, zsil, xsbf, nullptr, nullptr);
  // 3. depthwise conv + silu -> xsc bf16
  conv_silu<<<(MROWS * D_INNER) / (256 * 4), 256, 0, stream>>>(xsbf, cw, cb, xscbf);
  // 4. GEMM2: x_dbl = xsc @ x_proj^T, split-K=8 partials (64-row tiles, 512 blocks)
  gemm_bt<1, 64><<<dim3(64, 1, KZ2), 256, 0, stream>>>(
      xscbf, xpwbf, MROWS, 96, D_INNER, D_INNER / KZ2,
      xdbl8, nullptr, nullptr, nullptr, nullptr);
  xdbl_finish<<<(MROWS * 96) / 256, 256, 0, stream>>>(xdbl8, dtrbf, bc);
  // 5. GEMM3: dt = softplus(dt_r @ dt_proj^T + b) -> fp16   (64-row tiles, 1024 blocks)
  gemm_bt<2, 64><<<dim3(64, 16), 256, 0, stream>>>(
      dtrbf, dtwbf, MROWS, D_INNER, DT_RANK, DT_RANK,
      nullptr, nullptr, nullptr, dtbuf, dtb);
  // 6-8. chunked selective scan
  scan_pass1<<<dim3(8, NC, 2), 256, 0, stream>>>(dtbuf, xscbf, bc, Aneg, hfin, Pbuf);
  scan_pass2<<<256, 256, 0, stream>>>(hfin, Pbuf);
  scan_pass3<<<dim3(8, NC, 2), 256, 0, stream>>>(dtbuf, xscbf, bc, Aneg, hfin, Dv, zsil, ybf);
  // 9. GEMM4: out = y @ out_proj^T   (64-row tiles, 512 blocks)
  gemm_bt<3, 64><<<dim3(64, 8), 256, 0, stream>>>(
      ybf, owbf, MROWS, D_MODEL, D_INNER, D_INNER,
      out, nullptr, nullptr, nullptr, nullptr);
}

// Round 6
// 235.221 us; speedup vs baseline: 1.4273x; 1.0460x over previous
//
#include <hip/hip_runtime.h>
#include <hip/hip_bf16.h>
#include <hip/hip_fp16.h>
#include <stdint.h>

typedef __attribute__((ext_vector_type(8))) short s16x8;
typedef __attribute__((ext_vector_type(4))) float f32x4;
typedef __attribute__((ext_vector_type(4))) unsigned short u16x4;

#define D_MODEL 1024
#define D_INNER 2048
#define DT_RANK 64
#define NSTATE 16
#define BATCH 2
#define SEQ 2048
#define MROWS (BATCH*SEQ)   // 4096
#define NC 32
#define CLEN (SEQ/NC)       // 64
#define KZ2 8               // GEMM2 split-K factor

__device__ __forceinline__ float fsigmoid(float v) { return 1.f / (1.f + __expf(-v)); }

__device__ __forceinline__ unsigned short f2bf(float f) {
  __hip_bfloat16 h = __float2bfloat16(f);
  return *(unsigned short*)&h;
}

__device__ __forceinline__ float bf2f(unsigned short u) {
  return __uint_as_float(((unsigned int)u) << 16);
}

__device__ __forceinline__ void gl_lds16(const void* g, void* l) {
  __builtin_amdgcn_global_load_lds(
      (const __attribute__((address_space(1))) void*)g,
      (__attribute__((address_space(3))) void*)l, 16, 0, 0);
}

// ---------- setup: fp32->bf16 conversions + A = -exp(A_log), 8 elems/thread ----------
__global__ __launch_bounds__(256) void setup_convert(
    const float* __restrict__ x, const float* __restrict__ ipw,
    const float* __restrict__ xpw, const float* __restrict__ dtw,
    const float* __restrict__ opw, const float* __restrict__ alog,
    __hip_bfloat16* __restrict__ xbf, __hip_bfloat16* __restrict__ wbf,
    __hip_bfloat16* __restrict__ xpwbf, __hip_bfloat16* __restrict__ dtwbf,
    __hip_bfloat16* __restrict__ owbf, float* __restrict__ Aneg) {
  const int i = (blockIdx.x * 256 + threadIdx.x) * 8;
  const int n0 = MROWS * D_MODEL;               // x
  const int n1 = n0 + 2 * D_INNER * D_MODEL;    // in_proj
  const int n2 = n1 + 96 * D_INNER;             // x_proj
  const int n3 = n2 + D_INNER * DT_RANK;        // dt_proj
  const int n4 = n3 + D_MODEL * D_INNER;        // out_proj
  const int n5 = n4 + D_INNER * NSTATE;         // A_log
  const float* src; __hip_bfloat16* dst; int j;
  if (i < n0)      { src = x;    dst = xbf;   j = i; }
  else if (i < n1) { src = ipw;  dst = wbf;   j = i - n0; }
  else if (i < n2) { src = xpw;  dst = xpwbf; j = i - n1; }
  else if (i < n3) { src = dtw;  dst = dtwbf; j = i - n2; }
  else if (i < n4) { src = opw;  dst = owbf;  j = i - n3; }
  else if (i < n5) {
    int j2 = i - n4;
    float4 a = *(const float4*)(alog + j2);
    float4 b = *(const float4*)(alog + j2 + 4);
    float4 oa = {-expf(a.x), -expf(a.y), -expf(a.z), -expf(a.w)};
    float4 ob = {-expf(b.x), -expf(b.y), -expf(b.z), -expf(b.w)};
    *(float4*)(Aneg + j2) = oa;
    *(float4*)(Aneg + j2 + 4) = ob;
    return;
  } else return;
  float4 a = *(const float4*)(src + j);
  float4 b = *(const float4*)(src + j + 4);
  union { s16x8 v; unsigned short u[8]; } o;
  o.u[0] = f2bf(a.x); o.u[1] = f2bf(a.y); o.u[2] = f2bf(a.z); o.u[3] = f2bf(a.w);
  o.u[4] = f2bf(b.x); o.u[5] = f2bf(b.y); o.u[6] = f2bf(b.z); o.u[7] = f2bf(b.w);
  *(s16x8*)(dst + j) = o.v;
}

// ======================================================================
// GEMM1: 256x256 tile, BK=64, 8 waves (2Mx4N), 8-phase schedule with
// counted vmcnt (T3+T4), st_16x32 LDS XOR-swizzle (T2), setprio (T5).
// C[4096][4096] = A[4096][1024] * Bw[4096][1024]^T; cols<2048 -> xs bf16,
// cols>=2048 -> silu -> zsil bf16. LDS: 2 buf x (A 32KB + B 32KB) = 128KB.
// Staging: linear gl_lds dest + inverse-swizzled global source (rule #21);
// reads swizzle byte ^= ((row>>2)&1)<<5. Stage of tile t+2 goes into the
// buffer being read at iter t, AFTER the region's reads complete:
// B-stage in P3 (B reads done by P2-end), A-stage in P4 (done by P3-end).
// vmcnt(8) per iter = 8 staging loads in flight (never drains mid-loop).
// ======================================================================
#define K1 1024
__device__ __forceinline__ void stage_tile1(const __hip_bfloat16* __restrict__ src,
                                            int row0, unsigned short* ldsbase,
                                            int k0, int wave, int lane) {
#pragma unroll
  for (int j = 0; j < 4; ++j) {
    const int s = j * 512 + wave * 64 + lane;          // linear 16B slot
    const int sp = s ^ (((s >> 5) & 1) << 1);          // inverse swizzle
    const int row = sp >> 3, c8 = sp & 7;
    gl_lds16(src + (size_t)(row0 + row) * K1 + k0 + c8 * 8,
             ldsbase + (size_t)(j * 512 + wave * 64) * 8);
  }
}

__global__ __launch_bounds__(512, 2)
void gemm1_8ph(const __hip_bfloat16* __restrict__ A,
               const __hip_bfloat16* __restrict__ Bw,
               __hip_bfloat16* __restrict__ xsbf,
               __hip_bfloat16* __restrict__ zsil) {
  __shared__ unsigned short lds[65536];  // 131072 B: [buf][A 16K shorts][B 16K shorts]
  const int m0 = blockIdx.y * 256;
  const int n0 = blockIdx.x * 256;
  const int tid = threadIdx.x;
  const int lane = tid & 63;
  const int wave = tid >> 6;
  const int wr = wave >> 2;        // 0..1 (M)
  const int wc = wave & 3;         // 0..3 (N)
  const int lr = lane & 15;
  const int kh = lane >> 4;        // 0..3

  f32x4 acc[8][4] = {};
  s16x8 af[4][2], bfr[4][2];

  const int NT = K1 / 64;  // 16 K-tiles

  // prologue: stage tiles 0 (buf0) and 1 (buf1), full drain once
  stage_tile1(A,  m0, lds, 0, wave, lane);
  stage_tile1(Bw, n0, lds + 16384, 0, wave, lane);
  stage_tile1(A,  m0, lds + 32768, 64, wave, lane);
  stage_tile1(Bw, n0, lds + 32768 + 16384, 64, wave, lane);
  asm volatile("s_waitcnt vmcnt(0)" ::: "memory");
  __builtin_amdgcn_s_barrier();
  __builtin_amdgcn_sched_barrier(0);

  for (int t = 0; t < NT; ++t) {
    const int buf = t & 1;
    const char* abase = (const char*)lds + buf * 65536;
    const char* bbase = abase + 32768;
    const bool st = (t < NT - 2);
    const int k2 = (t + 2) * 64;

    // ---- P1: read af(mf0-3)+bfr(nf0-1); MFMA Q0 ----
#pragma unroll
    for (int f = 0; f < 4; ++f) {
      const int row = wr * 128 + f * 16 + lr;
      const int sw = ((row >> 2) & 1) << 5;
#pragma unroll
      for (int ks = 0; ks < 2; ++ks)
        af[f][ks] = *(const s16x8*)(abase + row * 128 + ((ks * 64 + kh * 16) ^ sw));
    }
#pragma unroll
    for (int g = 0; g < 2; ++g) {
      const int row = wc * 64 + g * 16 + lr;
      const int sw = ((row >> 2) & 1) << 5;
#pragma unroll
      for (int ks = 0; ks < 2; ++ks)
        bfr[g][ks] = *(const s16x8*)(bbase + row * 128 + ((ks * 64 + kh * 16) ^ sw));
    }
    __builtin_amdgcn_s_barrier();
    __builtin_amdgcn_sched_barrier(0);
    __builtin_amdgcn_s_setprio(1);
#pragma unroll
    for (int f = 0; f < 4; ++f)
#pragma unroll
      for (int g = 0; g < 2; ++g)
#pragma unroll
        for (int ks = 0; ks < 2; ++ks)
          acc[f][g] = __builtin_amdgcn_mfma_f32_16x16x32_bf16(bfr[g][ks], af[f][ks], acc[f][g], 0, 0, 0);
    __builtin_amdgcn_s_setprio(0);
    __builtin_amdgcn_s_barrier();
    __builtin_amdgcn_sched_barrier(0);

    // ---- P2: read bfr(nf2-3); MFMA Q1 ----
#pragma unroll
    for (int g = 2; g < 4; ++g) {
      const int row = wc * 64 + g * 16 + lr;
      const int sw = ((row >> 2) & 1) << 5;
#pragma unroll
      for (int ks = 0; ks < 2; ++ks)
        bfr[g][ks] = *(const s16x8*)(bbase + row * 128 + ((ks * 64 + kh * 16) ^ sw));
    }
    __builtin_amdgcn_s_barrier();
    __builtin_amdgcn_sched_barrier(0);
    __builtin_amdgcn_s_setprio(1);
#pragma unroll
    for (int f = 0; f < 4; ++f)
#pragma unroll
      for (int g = 2; g < 4; ++g)
#pragma unroll
        for (int ks = 0; ks < 2; ++ks)
          acc[f][g] = __builtin_amdgcn_mfma_f32_16x16x32_bf16(bfr[g][ks], af[f][ks], acc[f][g], 0, 0, 0);
    __builtin_amdgcn_s_setprio(0);
    __builtin_amdgcn_s_barrier();
    __builtin_amdgcn_sched_barrier(0);

    // ---- P3: read af(mf4-7, reusing regs); stage B(t+2); MFMA Q2 ----
#pragma unroll
    for (int f = 0; f < 4; ++f) {
      const int row = wr * 128 + 64 + f * 16 + lr;
      const int sw = ((row >> 2) & 1) << 5;
#pragma unroll
      for (int ks = 0; ks < 2; ++ks)
        af[f][ks] = *(const s16x8*)(abase + row * 128 + ((ks * 64 + kh * 16) ^ sw));
    }
    if (st) stage_tile1(Bw, n0, lds + buf * 32768 + 16384, k2, wave, lane);
    __builtin_amdgcn_s_barrier();
    __builtin_amdgcn_sched_barrier(0);
    __builtin_amdgcn_s_setprio(1);
#pragma unroll
    for (int f = 0; f < 4; ++f)
#pragma unroll
      for (int g = 0; g < 2; ++g)
#pragma unroll
        for (int ks = 0; ks < 2; ++ks)
          acc[4 + f][g] = __builtin_amdgcn_mfma_f32_16x16x32_bf16(bfr[g][ks], af[f][ks], acc[4 + f][g], 0, 0, 0);
    __builtin_amdgcn_s_setprio(0);
    __builtin_amdgcn_s_barrier();
    __builtin_amdgcn_sched_barrier(0);

    // ---- P4: stage A(t+2); MFMA Q3; counted vmcnt ----
    if (st) stage_tile1(A, m0, lds + buf * 32768, k2, wave, lane);
    __builtin_amdgcn_s_barrier();
    __builtin_amdgcn_sched_barrier(0);
    __builtin_amdgcn_s_setprio(1);
#pragma unroll
    for (int f = 0; f < 4; ++f)
#pragma unroll
      for (int g = 2; g < 4; ++g)
#pragma unroll
        for (int ks = 0; ks < 2; ++ks)
          acc[4 + f][g] = __builtin_amdgcn_mfma_f32_16x16x32_bf16(bfr[g][ks], af[f][ks], acc[4 + f][g], 0, 0, 0);
    __builtin_amdgcn_s_setprio(0);
    if (t < NT - 2) {
      asm volatile("s_waitcnt vmcnt(8)" ::: "memory");
    } else if (t == NT - 2) {
      asm volatile("s_waitcnt vmcnt(0)" ::: "memory");
    }
    if (t < NT - 1) {
      __builtin_amdgcn_s_barrier();
      __builtin_amdgcn_sched_barrier(0);
    }
  }

  // epilogue: lane holds C[m][nb..nb+3]; tile is entirely xs-half or z-half
  const bool isz = (n0 >= D_INNER);
  unsigned short* outp = (unsigned short*)(isz ? zsil : xsbf);
  const int nc0 = isz ? (n0 - D_INNER) : n0;
#pragma unroll
  for (int mf = 0; mf < 8; ++mf) {
    const int m = m0 + wr * 128 + mf * 16 + lr;
#pragma unroll
    for (int nf = 0; nf < 4; ++nf) {
      const int nb = nc0 + wc * 64 + nf * 16 + (lane >> 4) * 4;
      f32x4 v = acc[mf][nf];
      u16x4 o;
      if (isz) {
#pragma unroll
        for (int j = 0; j < 4; ++j) { float s = v[j] * fsigmoid(v[j]); o[j] = f2bf(s); }
      } else {
#pragma unroll
        for (int j = 0; j < 4; ++j) o[j] = f2bf(v[j]);
      }
      *(u16x4*)(outp + (size_t)m * D_INNER + nb) = o;
    }
  }
}

// ---------- m97-structure bf16 MFMA GEMM (kept for GEMM2/3/4) ----------
// MODE 1: GEMM2 (x_proj, split-K): fp32 partials, e0[(kz*M + m)*96 + nb]
// MODE 2: GEMM3 (dt_proj): +bias, softplus -> dt fp16 (eh)
// MODE 3: GEMM4 (out_proj): plain fp32 store
template<int MODE, int BM>
__global__ __launch_bounds__(256)
void gemm_bt(const __hip_bfloat16* __restrict__ A,
             const __hip_bfloat16* __restrict__ Bw,
             int M, int N, int K, int kchunk,
             float* __restrict__ e0,
             __half* __restrict__ eh,
             const float* __restrict__ bias) {
  constexpr int FM = BM / 32;
  constexpr int ABUF = BM * 32;
  constexpr int AW = ABUF / 4;
  constexpr int AI = BM / 64;
  __shared__ unsigned short As[2 * ABUF];
  __shared__ unsigned short Bs[2 * 128 * 32];
  const int m0 = blockIdx.x * BM;
  const int n0 = blockIdx.y * 128;
  const int kz = blockIdx.z;
  const int kb = kz * kchunk;
  const int nt = kchunk >> 5;
  const int tid = threadIdx.x;
  const int lane = tid & 63;
  const int wave = tid >> 6;
  const int wr = wave >> 1, wc = wave & 1;
  const int lrow = lane & 15;
  const int kh = lane >> 4;
  const int srow = lane >> 2;
  const int sc8 = (lane & 3) * 8;

  f32x4 acc[FM][4] = {};

  auto STAGE = [&](int buf, int k0) {
#pragma unroll
    for (int i = 0; i < AI; ++i) {
      const int row = wave * (AW / 32) + i * 16 + srow;
      gl_lds16(A + (size_t)(m0 + row) * K + k0 + sc8,
               As + buf * ABUF + wave * AW + i * 512);
    }
#pragma unroll
    for (int i = 0; i < 2; ++i) {
      const int row = wave * 32 + i * 16 + srow;
      int brow = n0 + row; if (brow >= N) brow = N - 1;
      gl_lds16(Bw + (size_t)brow * K + k0 + sc8,
               Bs + buf * 4096 + wave * 1024 + i * 512);
    }
  };

  STAGE(0, kb);
  __syncthreads();

  for (int t = 0; t < nt; ++t) {
    const int cur = t & 1;
    if (t + 1 < nt) STAGE(cur ^ 1, kb + ((t + 1) << 5));
    s16x8 af[FM], bfr[4];
#pragma unroll
    for (int f = 0; f < FM; ++f)
      af[f] = *(const s16x8*)(As + cur * ABUF + (wr * (BM / 2) + f * 16 + lrow) * 32 + kh * 8);
#pragma unroll
    for (int g = 0; g < 4; ++g)
      bfr[g] = *(const s16x8*)(Bs + cur * 4096 + (wc * 64 + g * 16 + lrow) * 32 + kh * 8);
#pragma unroll
    for (int f = 0; f < FM; ++f)
#pragma unroll
      for (int g = 0; g < 4; ++g)
        acc[f][g] = __builtin_amdgcn_mfma_f32_16x16x32_bf16(bfr[g], af[f], acc[f][g], 0, 0, 0);
    if (t + 1 < nt) __syncthreads();
  }

#pragma unroll
  for (int f = 0; f < FM; ++f) {
    const int m = m0 + wr * (BM / 2) + f * 16 + (lane & 15);
#pragma unroll
    for (int g = 0; g < 4; ++g) {
      const int nb = n0 + wc * 64 + g * 16 + (lane >> 4) * 4;
      f32x4 v = acc[f][g];
      if (MODE == 1) {
        if (nb < 96) {
          float4 r = {v[0], v[1], v[2], v[3]};
          *(float4*)(e0 + ((size_t)kz * MROWS + m) * 96 + nb) = r;
        }
      } else if (MODE == 2) {
        float4 bb = *(const float4*)(bias + nb);
        u16x4 o;
        float t0 = v[0] + bb.x; float r0 = (t0 > 20.f) ? t0 : __logf(1.f + __expf(t0));
        float t1 = v[1] + bb.y; float r1 = (t1 > 20.f) ? t1 : __logf(1.f + __expf(t1));
        float t2 = v[2] + bb.z; float r2 = (t2 > 20.f) ? t2 : __logf(1.f + __expf(t2));
        float t3 = v[3] + bb.w; float r3 = (t3 > 20.f) ? t3 : __logf(1.f + __expf(t3));
        o[0] = __half_as_ushort(__float2half(r0));
        o[1] = __half_as_ushort(__float2half(r1));
        o[2] = __half_as_ushort(__float2half(r2));
        o[3] = __half_as_ushort(__float2half(r3));
        *(u16x4*)((unsigned short*)eh + (size_t)m * D_INNER + nb) = o;
      } else {
        float4 r = {v[0], v[1], v[2], v[3]};
        *(float4*)(e0 + (size_t)m * D_MODEL + nb) = r;
      }
    }
  }
}

// ---------- reduce 8 split-K partials -> dt_r (bf16) + B/C (fp32) ----------
__global__ __launch_bounds__(256)
void xdbl_finish(const float* __restrict__ xdbl8, __hip_bfloat16* __restrict__ dtrbf,
                 float* __restrict__ bc) {
  int i = blockIdx.x * 256 + threadIdx.x;  // 4096*96
  int r = i / 96, c = i - r * 96;
  float v = 0.f;
#pragma unroll
  for (int p = 0; p < KZ2; ++p) v += xdbl8[(size_t)p * (MROWS * 96) + i];
  if (c < DT_RANK) dtrbf[r * DT_RANK + c] = __float2bfloat16(v);
  else bc[r * 32 + (c - DT_RANK)] = v;
}

// ---------- depthwise causal conv (k=4) + bias + silu, 4 channels/thread ----------
__global__ __launch_bounds__(256)
void conv_silu(const __hip_bfloat16* __restrict__ xsb, const float* __restrict__ cw,
               const float* __restrict__ cb,
               __hip_bfloat16* __restrict__ xscbf) {
  const int g = blockIdx.x * 256 + threadIdx.x;
  const int idx = g * 4;
  const int l = (idx >> 11) & (SEQ - 1);
  const int d = idx & (D_INNER - 1);
  const unsigned short* p = (const unsigned short*)xsb + idx;
  float4 xm3 = {0.f, 0.f, 0.f, 0.f}, xm2 = xm3, xm1 = xm3, x0;
  {
    u16x4 u = *(const u16x4*)(p);
    x0.x = bf2f(u[0]); x0.y = bf2f(u[1]); x0.z = bf2f(u[2]); x0.w = bf2f(u[3]);
  }
  if (l >= 1) { u16x4 u = *(const u16x4*)(p - 1 * D_INNER);
    xm1.x = bf2f(u[0]); xm1.y = bf2f(u[1]); xm1.z = bf2f(u[2]); xm1.w = bf2f(u[3]); }
  if (l >= 2) { u16x4 u = *(const u16x4*)(p - 2 * D_INNER);
    xm2.x = bf2f(u[0]); xm2.y = bf2f(u[1]); xm2.z = bf2f(u[2]); xm2.w = bf2f(u[3]); }
  if (l >= 3) { u16x4 u = *(const u16x4*)(p - 3 * D_INNER);
    xm3.x = bf2f(u[0]); xm3.y = bf2f(u[1]); xm3.z = bf2f(u[2]); xm3.w = bf2f(u[3]); }
  const float4* cwv = (const float4*)(cw + d * 4);
  float4 cb4 = *(const float4*)(cb + d);
  float4 out;
  { float4 q = cwv[0]; out.x = cb4.x + q.x * xm3.x + q.y * xm2.x + q.z * xm1.x + q.w * x0.x; }
  { float4 q = cwv[1]; out.y = cb4.y + q.x * xm3.y + q.y * xm2.y + q.z * xm1.y + q.w * x0.y; }
  { float4 q = cwv[2]; out.z = cb4.z + q.x * xm3.z + q.y * xm2.z + q.z * xm1.z + q.w * x0.z; }
  { float4 q = cwv[3]; out.w = cb4.w + q.x * xm3.w + q.y * xm2.w + q.z * xm1.w + q.w * x0.w; }
  out.x *= fsigmoid(out.x); out.y *= fsigmoid(out.y);
  out.z *= fsigmoid(out.z); out.w *= fsigmoid(out.w);
  u16x4 ob = {f2bf(out.x), f2bf(out.y), f2bf(out.z), f2bf(out.w)};
  *(u16x4*)((unsigned short*)xscbf + idx) = ob;
}

// ---------- scan pass 1: per-chunk final state + decay product (h0=0) ----------
__global__ __launch_bounds__(256)
void scan_pass1(const __half* __restrict__ dt, const __hip_bfloat16* __restrict__ xsc,
                const float* __restrict__ bc, const float* __restrict__ Aneg,
                float* __restrict__ hfin, float* __restrict__ Pbuf) {
  const int b = blockIdx.z, c = blockIdx.y;
  const int d = blockIdx.x * 256 + threadIdx.x;
  __shared__ float BC[CLEN][32];
  const size_t mrow0 = (size_t)b * SEQ + (size_t)c * CLEN;
  for (int t = threadIdx.x; t < CLEN * 32; t += 256) {
    int i = t >> 5, col = t & 31;
    BC[i][col] = bc[(mrow0 + i) * 32 + col];
  }
  __syncthreads();
  float Ar[16];
#pragma unroll
  for (int n = 0; n < 16; ++n) Ar[n] = Aneg[d * 16 + n];
  float h[16];
#pragma unroll
  for (int n = 0; n < 16; ++n) h[n] = 0.f;
  float dtsum = 0.f;
  size_t base = mrow0 * D_INNER + d;
  for (int l = 0; l < CLEN; ++l) {
    float dtv = __half2float(dt[base + (size_t)l * D_INNER]);
    float u = dtv * bf2f(((const unsigned short*)xsc)[base + (size_t)l * D_INNER]);
    dtsum += dtv;
#pragma unroll
    for (int n = 0; n < 16; ++n) {
      float a = __expf(dtv * Ar[n]);
      h[n] = h[n] * a + u * BC[l][n];
    }
  }
  size_t o = (((size_t)b * NC + c) * D_INNER + d) * 16;
#pragma unroll
  for (int n = 0; n < 16; ++n) { hfin[o + n] = h[n]; Pbuf[o + n] = __expf(dtsum * Ar[n]); }
}

// ---------- scan pass 2: cross-chunk combine ----------
__global__ __launch_bounds__(256)
void scan_pass2(float* __restrict__ hfin, const float* __restrict__ Pbuf) {
  int idx = blockIdx.x * 256 + threadIdx.x;
  int b = idx >> 15;
  int dn = idx & 32767;
  float h0 = 0.f;
  for (int c = 0; c < NC; ++c) {
    size_t o = ((size_t)b * NC + c) * 32768 + dn;
    float hf = hfin[o], p = Pbuf[o];
    hfin[o] = h0;
    h0 = hf + p * h0;
  }
}

// ---------- scan pass 3: re-run chunk from h_init, emit y bf16 ----------
__global__ __launch_bounds__(256)
void scan_pass3(const __half* __restrict__ dt, const __hip_bfloat16* __restrict__ xsc,
                const float* __restrict__ bc, const float* __restrict__ Aneg,
                const float* __restrict__ hinit, const float* __restrict__ Dv,
                const __hip_bfloat16* __restrict__ zsil,
                __hip_bfloat16* __restrict__ ybf) {
  const int b = blockIdx.z, c = blockIdx.y;
  const int d = blockIdx.x * 256 + threadIdx.x;
  __shared__ float BC[CLEN][32];
  const size_t mrow0 = (size_t)b * SEQ + (size_t)c * CLEN;
  for (int t = threadIdx.x; t < CLEN * 32; t += 256) {
    int i = t >> 5, col = t & 31;
    BC[i][col] = bc[(mrow0 + i) * 32 + col];
  }
  __syncthreads();
  float Ar[16];
#pragma unroll
  for (int n = 0; n < 16; ++n) Ar[n] = Aneg[d * 16 + n];
  float h[16];
  size_t o = (((size_t)b * NC + c) * D_INNER + d) * 16;
#pragma unroll
  for (int n = 0; n < 16; ++n) h[n] = hinit[o + n];
  const float dval = Dv[d];
  size_t base = mrow0 * D_INNER + d;
  for (int l = 0; l < CLEN; ++l) {
    float dtv = __half2float(dt[base + (size_t)l * D_INNER]);
    float xv = bf2f(((const unsigned short*)xsc)[base + (size_t)l * D_INNER]);
    float u = dtv * xv;
    float y = 0.f;
#pragma unroll
    for (int n = 0; n < 16; ++n) {
      float a = __expf(dtv * Ar[n]);
      h[n] = h[n] * a + u * BC[l][n];
      y += h[n] * BC[l][16 + n];
    }
    float yo = y + xv * dval;
    float zg = __bfloat162float(zsil[base + (size_t)l * D_INNER]);
    ybf[base + (size_t)l * D_INNER] = __float2bfloat16(yo * zg);
  }
}

extern "C" void kernel_launch(void* const* d_in, const int* in_sizes, int n_in,
                              void* d_out, int out_size, void* d_ws, size_t ws_size,
                              hipStream_t stream) {
  const float* x    = (const float*)d_in[0];
  const float* ipw  = (const float*)d_in[1];
  const float* cw   = (const float*)d_in[2];
  const float* cb   = (const float*)d_in[3];
  const float* xpw  = (const float*)d_in[4];
  const float* dtw  = (const float*)d_in[5];
  const float* dtb  = (const float*)d_in[6];
  const float* alog = (const float*)d_in[7];
  const float* Dv   = (const float*)d_in[8];
  const float* opw  = (const float*)d_in[9];
  float* out = (float*)d_out;

  char* w = (char*)d_ws;
  __hip_bfloat16* xbf   = (__hip_bfloat16*)(w + 0);          //  8,388,608
  __hip_bfloat16* wbf   = (__hip_bfloat16*)(w + 8388608);    //  8,388,608
  __hip_bfloat16* ybf   = (__hip_bfloat16*)(w + 0);          // 16,777,216 (alias)
  __hip_bfloat16* owbf  = (__hip_bfloat16*)(w + 16777216);   //  4,194,304
  __hip_bfloat16* xpwbf = (__hip_bfloat16*)(w + 20971520);   //    393,216
  __hip_bfloat16* dtwbf = (__hip_bfloat16*)(w + 21364736);   //    262,144
  float* Aneg           = (float*)(w + 21626880);            //    131,072
  __hip_bfloat16* xsbf  = (__hip_bfloat16*)(w + 21757952);   // 16,777,216
  __half* dtbuf         = (__half*)(w + 21757952);           // 16,777,216 (alias)
  __hip_bfloat16* zsil  = (__hip_bfloat16*)(w + 55312384);   // 16,777,216
  __hip_bfloat16* xscbf = (__hip_bfloat16*)(w + 105644032);  // 16,777,216
  __hip_bfloat16* dtrbf = (__hip_bfloat16*)(w + 122421248);  //    524,288
  float* bc             = (float*)(w + 122945536);           //    524,288
  float* hfin           = (float*)(w + 123469824);           //  8,388,608
  float* Pbuf           = (float*)(w + 131858432);           //  8,388,608
  float* xdbl8          = (float*)(w + 123469824);           // 12,582,912 (alias)

  // 1. convert inputs to bf16 (+ A = -exp(A_log))
  {
    const int total = MROWS * D_MODEL + 2 * D_INNER * D_MODEL + 96 * D_INNER +
                      D_INNER * DT_RANK + D_MODEL * D_INNER + D_INNER * NSTATE;
    setup_convert<<<total / (256 * 8), 256, 0, stream>>>(
        x, ipw, xpw, dtw, opw, alog, xbf, wbf, xpwbf, dtwbf, owbf, Aneg);
  }
  // 2. GEMM1 (8-phase 256² schedule): xz = x @ in_proj^T -> xs bf16, silu(z) bf16
  gemm1_8ph<<<dim3(16, 16), 512, 0, stream>>>(xbf, wbf, xsbf, zsil);
  // 3. depthwise conv + silu -> xsc bf16
  conv_silu<<<(MROWS * D_INNER) / (256 * 4), 256, 0, stream>>>(xsbf, cw, cb, xscbf);
  // 4. GEMM2: x_dbl = xsc @ x_proj^T, split-K=8 partials + reduce
  gemm_bt<1, 64><<<dim3(64, 1, KZ2), 256, 0, stream>>>(
      xscbf, xpwbf, MROWS, 96, D_INNER, D_INNER / KZ2,
      xdbl8, nullptr, nullptr);
  xdbl_finish<<<(MROWS * 96) / 256, 256, 0, stream>>>(xdbl8, dtrbf, bc);
  // 5. GEMM3: dt = softplus(dt_r @ dt_proj^T + b) -> fp16
  gemm_bt<2, 64><<<dim3(64, 16), 256, 0, stream>>>(
      dtrbf, dtwbf, MROWS, D_INNER, DT_RANK, DT_RANK,
      nullptr, dtbuf, dtb);
  // 6-8. chunked selective scan
  scan_pass1<<<dim3(8, NC, 2), 256, 0, stream>>>(dtbuf, xscbf, bc, Aneg, hfin, Pbuf);
  scan_pass2<<<256, 256, 0, stream>>>(hfin, Pbuf);
  scan_pass3<<<dim3(8, NC, 2), 256, 0, stream>>>(dtbuf, xscbf, bc, Aneg, hfin, Dv, zsil, ybf);
  // 9. GEMM4: out = y @ out_proj^T
  gemm_bt<3, 64><<<dim3(64, 8), 256, 0, stream>>>(
      ybf, owbf, MROWS, D_MODEL, D_INNER, D_INNER,
      out, nullptr, nullptr);
}

// Round 7
// 217.008 us; speedup vs baseline: 1.5471x; 1.0839x over previous
//
#include <hip/hip_runtime.h>
#include <hip/hip_bf16.h>
#include <hip/hip_fp16.h>
#include <stdint.h>

typedef __attribute__((ext_vector_type(8))) short s16x8;
typedef __attribute__((ext_vector_type(4))) float f32x4;
typedef __attribute__((ext_vector_type(4))) unsigned short u16x4;

#define D_MODEL 1024
#define D_INNER 2048
#define DT_RANK 64
#define NSTATE 16
#define BATCH 2
#define SEQ 2048
#define MROWS (BATCH*SEQ)   // 4096
#define NC 64
#define CLEN (SEQ/NC)       // 32
#define KZ2 8               // GEMM2 split-K factor

__device__ __forceinline__ float fsigmoid(float v) { return 1.f / (1.f + __expf(-v)); }

__device__ __forceinline__ unsigned short f2bf(float f) {
  __hip_bfloat16 h = __float2bfloat16(f);
  return *(unsigned short*)&h;
}

__device__ __forceinline__ float bf2f(unsigned short u) {
  return __uint_as_float(((unsigned int)u) << 16);
}

__device__ __forceinline__ void gl_lds16(const void* g, void* l) {
  __builtin_amdgcn_global_load_lds(
      (const __attribute__((address_space(1))) void*)g,
      (__attribute__((address_space(3))) void*)l, 16, 0, 0);
}

// ---------- setup: fp32->bf16 conversions + A = -exp(A_log), 8 elems/thread ----------
__global__ __launch_bounds__(256) void setup_convert(
    const float* __restrict__ x, const float* __restrict__ ipw,
    const float* __restrict__ xpw, const float* __restrict__ dtw,
    const float* __restrict__ opw, const float* __restrict__ alog,
    __hip_bfloat16* __restrict__ xbf, __hip_bfloat16* __restrict__ wbf,
    __hip_bfloat16* __restrict__ xpwbf, __hip_bfloat16* __restrict__ dtwbf,
    __hip_bfloat16* __restrict__ owbf, float* __restrict__ Aneg) {
  const int i = (blockIdx.x * 256 + threadIdx.x) * 8;
  const int n0 = MROWS * D_MODEL;               // x
  const int n1 = n0 + 2 * D_INNER * D_MODEL;    // in_proj
  const int n2 = n1 + 96 * D_INNER;             // x_proj
  const int n3 = n2 + D_INNER * DT_RANK;        // dt_proj
  const int n4 = n3 + D_MODEL * D_INNER;        // out_proj
  const int n5 = n4 + D_INNER * NSTATE;         // A_log
  const float* src; __hip_bfloat16* dst; int j;
  if (i < n0)      { src = x;    dst = xbf;   j = i; }
  else if (i < n1) { src = ipw;  dst = wbf;   j = i - n0; }
  else if (i < n2) { src = xpw;  dst = xpwbf; j = i - n1; }
  else if (i < n3) { src = dtw;  dst = dtwbf; j = i - n2; }
  else if (i < n4) { src = opw;  dst = owbf;  j = i - n3; }
  else if (i < n5) {
    int j2 = i - n4;
    float4 a = *(const float4*)(alog + j2);
    float4 b = *(const float4*)(alog + j2 + 4);
    float4 oa = {-expf(a.x), -expf(a.y), -expf(a.z), -expf(a.w)};
    float4 ob = {-expf(b.x), -expf(b.y), -expf(b.z), -expf(b.w)};
    *(float4*)(Aneg + j2) = oa;
    *(float4*)(Aneg + j2 + 4) = ob;
    return;
  } else return;
  float4 a = *(const float4*)(src + j);
  float4 b = *(const float4*)(src + j + 4);
  union { s16x8 v; unsigned short u[8]; } o;
  o.u[0] = f2bf(a.x); o.u[1] = f2bf(a.y); o.u[2] = f2bf(a.z); o.u[3] = f2bf(a.w);
  o.u[4] = f2bf(b.x); o.u[5] = f2bf(b.y); o.u[6] = f2bf(b.z); o.u[7] = f2bf(b.w);
  *(s16x8*)(dst + j) = o.v;
}

// ======================================================================
// GEMM1: 256x256 tile, BK=64, 8 waves (2Mx4N), 8-phase schedule with
// counted vmcnt (T3+T4), st_16x32 LDS XOR-swizzle (T2), setprio (T5).
// ======================================================================
#define K1 1024
__device__ __forceinline__ void stage_tile1(const __hip_bfloat16* __restrict__ src,
                                            int row0, unsigned short* ldsbase,
                                            int k0, int wave, int lane) {
#pragma unroll
  for (int j = 0; j < 4; ++j) {
    const int s = j * 512 + wave * 64 + lane;          // linear 16B slot
    const int sp = s ^ (((s >> 5) & 1) << 1);          // inverse swizzle
    const int row = sp >> 3, c8 = sp & 7;
    gl_lds16(src + (size_t)(row0 + row) * K1 + k0 + c8 * 8,
             ldsbase + (size_t)(j * 512 + wave * 64) * 8);
  }
}

__global__ __launch_bounds__(512, 2)
void gemm1_8ph(const __hip_bfloat16* __restrict__ A,
               const __hip_bfloat16* __restrict__ Bw,
               __hip_bfloat16* __restrict__ xsbf,
               __hip_bfloat16* __restrict__ zsil) {
  __shared__ unsigned short lds[65536];  // 131072 B
  const int m0 = blockIdx.y * 256;
  const int n0 = blockIdx.x * 256;
  const int tid = threadIdx.x;
  const int lane = tid & 63;
  const int wave = tid >> 6;
  const int wr = wave >> 2;
  const int wc = wave & 3;
  const int lr = lane & 15;
  const int kh = lane >> 4;

  f32x4 acc[8][4] = {};
  s16x8 af[4][2], bfr[4][2];

  const int NT = K1 / 64;  // 16

  stage_tile1(A,  m0, lds, 0, wave, lane);
  stage_tile1(Bw, n0, lds + 16384, 0, wave, lane);
  stage_tile1(A,  m0, lds + 32768, 64, wave, lane);
  stage_tile1(Bw, n0, lds + 32768 + 16384, 64, wave, lane);
  asm volatile("s_waitcnt vmcnt(0)" ::: "memory");
  __builtin_amdgcn_s_barrier();
  __builtin_amdgcn_sched_barrier(0);

  for (int t = 0; t < NT; ++t) {
    const int buf = t & 1;
    const char* abase = (const char*)lds + buf * 65536;
    const char* bbase = abase + 32768;
    const bool st = (t < NT - 2);
    const int k2 = (t + 2) * 64;

    // ---- P1 ----
#pragma unroll
    for (int f = 0; f < 4; ++f) {
      const int row = wr * 128 + f * 16 + lr;
      const int sw = ((row >> 2) & 1) << 5;
#pragma unroll
      for (int ks = 0; ks < 2; ++ks)
        af[f][ks] = *(const s16x8*)(abase + row * 128 + ((ks * 64 + kh * 16) ^ sw));
    }
#pragma unroll
    for (int g = 0; g < 2; ++g) {
      const int row = wc * 64 + g * 16 + lr;
      const int sw = ((row >> 2) & 1) << 5;
#pragma unroll
      for (int ks = 0; ks < 2; ++ks)
        bfr[g][ks] = *(const s16x8*)(bbase + row * 128 + ((ks * 64 + kh * 16) ^ sw));
    }
    __builtin_amdgcn_s_barrier();
    __builtin_amdgcn_sched_barrier(0);
    __builtin_amdgcn_s_setprio(1);
#pragma unroll
    for (int f = 0; f < 4; ++f)
#pragma unroll
      for (int g = 0; g < 2; ++g)
#pragma unroll
        for (int ks = 0; ks < 2; ++ks)
          acc[f][g] = __builtin_amdgcn_mfma_f32_16x16x32_bf16(bfr[g][ks], af[f][ks], acc[f][g], 0, 0, 0);
    __builtin_amdgcn_s_setprio(0);
    __builtin_amdgcn_s_barrier();
    __builtin_amdgcn_sched_barrier(0);

    // ---- P2 ----
#pragma unroll
    for (int g = 2; g < 4; ++g) {
      const int row = wc * 64 + g * 16 + lr;
      const int sw = ((row >> 2) & 1) << 5;
#pragma unroll
      for (int ks = 0; ks < 2; ++ks)
        bfr[g][ks] = *(const s16x8*)(bbase + row * 128 + ((ks * 64 + kh * 16) ^ sw));
    }
    __builtin_amdgcn_s_barrier();
    __builtin_amdgcn_sched_barrier(0);
    __builtin_amdgcn_s_setprio(1);
#pragma unroll
    for (int f = 0; f < 4; ++f)
#pragma unroll
      for (int g = 2; g < 4; ++g)
#pragma unroll
        for (int ks = 0; ks < 2; ++ks)
          acc[f][g] = __builtin_amdgcn_mfma_f32_16x16x32_bf16(bfr[g][ks], af[f][ks], acc[f][g], 0, 0, 0);
    __builtin_amdgcn_s_setprio(0);
    __builtin_amdgcn_s_barrier();
    __builtin_amdgcn_sched_barrier(0);

    // ---- P3 ----
#pragma unroll
    for (int f = 0; f < 4; ++f) {
      const int row = wr * 128 + 64 + f * 16 + lr;
      const int sw = ((row >> 2) & 1) << 5;
#pragma unroll
      for (int ks = 0; ks < 2; ++ks)
        af[f][ks] = *(const s16x8*)(abase + row * 128 + ((ks * 64 + kh * 16) ^ sw));
    }
    if (st) stage_tile1(Bw, n0, lds + buf * 32768 + 16384, k2, wave, lane);
    __builtin_amdgcn_s_barrier();
    __builtin_amdgcn_sched_barrier(0);
    __builtin_amdgcn_s_setprio(1);
#pragma unroll
    for (int f = 0; f < 4; ++f)
#pragma unroll
      for (int g = 0; g < 2; ++g)
#pragma unroll
        for (int ks = 0; ks < 2; ++ks)
          acc[4 + f][g] = __builtin_amdgcn_mfma_f32_16x16x32_bf16(bfr[g][ks], af[f][ks], acc[4 + f][g], 0, 0, 0);
    __builtin_amdgcn_s_setprio(0);
    __builtin_amdgcn_s_barrier();
    __builtin_amdgcn_sched_barrier(0);

    // ---- P4 ----
    if (st) stage_tile1(A, m0, lds + buf * 32768, k2, wave, lane);
    __builtin_amdgcn_s_barrier();
    __builtin_amdgcn_sched_barrier(0);
    __builtin_amdgcn_s_setprio(1);
#pragma unroll
    for (int f = 0; f < 4; ++f)
#pragma unroll
      for (int g = 2; g < 4; ++g)
#pragma unroll
        for (int ks = 0; ks < 2; ++ks)
          acc[4 + f][g] = __builtin_amdgcn_mfma_f32_16x16x32_bf16(bfr[g][ks], af[f][ks], acc[4 + f][g], 0, 0, 0);
    __builtin_amdgcn_s_setprio(0);
    if (t < NT - 2) {
      asm volatile("s_waitcnt vmcnt(8)" ::: "memory");
    } else if (t == NT - 2) {
      asm volatile("s_waitcnt vmcnt(0)" ::: "memory");
    }
    if (t < NT - 1) {
      __builtin_amdgcn_s_barrier();
      __builtin_amdgcn_sched_barrier(0);
    }
  }

  const bool isz = (n0 >= D_INNER);
  unsigned short* outp = (unsigned short*)(isz ? zsil : xsbf);
  const int nc0 = isz ? (n0 - D_INNER) : n0;
#pragma unroll
  for (int mf = 0; mf < 8; ++mf) {
    const int m = m0 + wr * 128 + mf * 16 + lr;
#pragma unroll
    for (int nf = 0; nf < 4; ++nf) {
      const int nb = nc0 + wc * 64 + nf * 16 + (lane >> 4) * 4;
      f32x4 v = acc[mf][nf];
      u16x4 o;
      if (isz) {
#pragma unroll
        for (int j = 0; j < 4; ++j) { float s = v[j] * fsigmoid(v[j]); o[j] = f2bf(s); }
      } else {
#pragma unroll
        for (int j = 0; j < 4; ++j) o[j] = f2bf(v[j]);
      }
      *(u16x4*)(outp + (size_t)m * D_INNER + nb) = o;
    }
  }
}

// ---------- m97-structure bf16 MFMA GEMM (GEMM2/3/4) ----------
template<int MODE, int BM>
__global__ __launch_bounds__(256)
void gemm_bt(const __hip_bfloat16* __restrict__ A,
             const __hip_bfloat16* __restrict__ Bw,
             int M, int N, int K, int kchunk,
             float* __restrict__ e0,
             __half* __restrict__ eh,
             const float* __restrict__ bias) {
  constexpr int FM = BM / 32;
  constexpr int ABUF = BM * 32;
  constexpr int AW = ABUF / 4;
  constexpr int AI = BM / 64;
  __shared__ unsigned short As[2 * ABUF];
  __shared__ unsigned short Bs[2 * 128 * 32];
  const int m0 = blockIdx.x * BM;
  const int n0 = blockIdx.y * 128;
  const int kz = blockIdx.z;
  const int kb = kz * kchunk;
  const int nt = kchunk >> 5;
  const int tid = threadIdx.x;
  const int lane = tid & 63;
  const int wave = tid >> 6;
  const int wr = wave >> 1, wc = wave & 1;
  const int lrow = lane & 15;
  const int kh = lane >> 4;
  const int srow = lane >> 2;
  const int sc8 = (lane & 3) * 8;

  f32x4 acc[FM][4] = {};

  auto STAGE = [&](int buf, int k0) {
#pragma unroll
    for (int i = 0; i < AI; ++i) {
      const int row = wave * (AW / 32) + i * 16 + srow;
      gl_lds16(A + (size_t)(m0 + row) * K + k0 + sc8,
               As + buf * ABUF + wave * AW + i * 512);
    }
#pragma unroll
    for (int i = 0; i < 2; ++i) {
      const int row = wave * 32 + i * 16 + srow;
      int brow = n0 + row; if (brow >= N) brow = N - 1;
      gl_lds16(Bw + (size_t)brow * K + k0 + sc8,
               Bs + buf * 4096 + wave * 1024 + i * 512);
    }
  };

  STAGE(0, kb);
  __syncthreads();

  for (int t = 0; t < nt; ++t) {
    const int cur = t & 1;
    if (t + 1 < nt) STAGE(cur ^ 1, kb + ((t + 1) << 5));
    s16x8 af[FM], bfr[4];
#pragma unroll
    for (int f = 0; f < FM; ++f)
      af[f] = *(const s16x8*)(As + cur * ABUF + (wr * (BM / 2) + f * 16 + lrow) * 32 + kh * 8);
#pragma unroll
    for (int g = 0; g < 4; ++g)
      bfr[g] = *(const s16x8*)(Bs + cur * 4096 + (wc * 64 + g * 16 + lrow) * 32 + kh * 8);
#pragma unroll
    for (int f = 0; f < FM; ++f)
#pragma unroll
      for (int g = 0; g < 4; ++g)
        acc[f][g] = __builtin_amdgcn_mfma_f32_16x16x32_bf16(bfr[g], af[f], acc[f][g], 0, 0, 0);
    if (t + 1 < nt) __syncthreads();
  }

#pragma unroll
  for (int f = 0; f < FM; ++f) {
    const int m = m0 + wr * (BM / 2) + f * 16 + (lane & 15);
#pragma unroll
    for (int g = 0; g < 4; ++g) {
      const int nb = n0 + wc * 64 + g * 16 + (lane >> 4) * 4;
      f32x4 v = acc[f][g];
      if (MODE == 1) {
        if (nb < 96) {
          float4 r = {v[0], v[1], v[2], v[3]};
          *(float4*)(e0 + ((size_t)kz * MROWS + m) * 96 + nb) = r;
        }
      } else if (MODE == 2) {
        float4 bb = *(const float4*)(bias + nb);
        u16x4 o;
        float t0 = v[0] + bb.x; float r0 = (t0 > 20.f) ? t0 : __logf(1.f + __expf(t0));
        float t1 = v[1] + bb.y; float r1 = (t1 > 20.f) ? t1 : __logf(1.f + __expf(t1));
        float t2 = v[2] + bb.z; float r2 = (t2 > 20.f) ? t2 : __logf(1.f + __expf(t2));
        float t3 = v[3] + bb.w; float r3 = (t3 > 20.f) ? t3 : __logf(1.f + __expf(t3));
        o[0] = __half_as_ushort(__float2half(r0));
        o[1] = __half_as_ushort(__float2half(r1));
        o[2] = __half_as_ushort(__float2half(r2));
        o[3] = __half_as_ushort(__float2half(r3));
        *(u16x4*)((unsigned short*)eh + (size_t)m * D_INNER + nb) = o;
      } else {
        float4 r = {v[0], v[1], v[2], v[3]};
        *(float4*)(e0 + (size_t)m * D_MODEL + nb) = r;
      }
    }
  }
}

// ---------- reduce 8 split-K partials -> dt_r (bf16) + B/C (fp32) ----------
__global__ __launch_bounds__(256)
void xdbl_finish(const float* __restrict__ xdbl8, __hip_bfloat16* __restrict__ dtrbf,
                 float* __restrict__ bc) {
  int i = blockIdx.x * 256 + threadIdx.x;  // 4096*96
  int r = i / 96, c = i - r * 96;
  float v = 0.f;
#pragma unroll
  for (int p = 0; p < KZ2; ++p) v += xdbl8[(size_t)p * (MROWS * 96) + i];
  if (c < DT_RANK) dtrbf[r * DT_RANK + c] = __float2bfloat16(v);
  else bc[r * 32 + (c - DT_RANK)] = v;
}

// ---------- depthwise causal conv (k=4) + bias + silu ----------
__global__ __launch_bounds__(256)
void conv_silu(const __hip_bfloat16* __restrict__ xsb, const float* __restrict__ cw,
               const float* __restrict__ cb,
               __hip_bfloat16* __restrict__ xscbf) {
  const int g = blockIdx.x * 256 + threadIdx.x;
  const int idx = g * 4;
  const int l = (idx >> 11) & (SEQ - 1);
  const int d = idx & (D_INNER - 1);
  const unsigned short* p = (const unsigned short*)xsb + idx;
  float4 xm3 = {0.f, 0.f, 0.f, 0.f}, xm2 = xm3, xm1 = xm3, x0;
  {
    u16x4 u = *(const u16x4*)(p);
    x0.x = bf2f(u[0]); x0.y = bf2f(u[1]); x0.z = bf2f(u[2]); x0.w = bf2f(u[3]);
  }
  if (l >= 1) { u16x4 u = *(const u16x4*)(p - 1 * D_INNER);
    xm1.x = bf2f(u[0]); xm1.y = bf2f(u[1]); xm1.z = bf2f(u[2]); xm1.w = bf2f(u[3]); }
  if (l >= 2) { u16x4 u = *(const u16x4*)(p - 2 * D_INNER);
    xm2.x = bf2f(u[0]); xm2.y = bf2f(u[1]); xm2.z = bf2f(u[2]); xm2.w = bf2f(u[3]); }
  if (l >= 3) { u16x4 u = *(const u16x4*)(p - 3 * D_INNER);
    xm3.x = bf2f(u[0]); xm3.y = bf2f(u[1]); xm3.z = bf2f(u[2]); xm3.w = bf2f(u[3]); }
  const float4* cwv = (const float4*)(cw + d * 4);
  float4 cb4 = *(const float4*)(cb + d);
  float4 out;
  { float4 q = cwv[0]; out.x = cb4.x + q.x * xm3.x + q.y * xm2.x + q.z * xm1.x + q.w * x0.x; }
  { float4 q = cwv[1]; out.y = cb4.y + q.x * xm3.y + q.y * xm2.y + q.z * xm1.y + q.w * x0.y; }
  { float4 q = cwv[2]; out.z = cb4.z + q.x * xm3.z + q.y * xm2.z + q.z * xm1.z + q.w * x0.z; }
  { float4 q = cwv[3]; out.w = cb4.w + q.x * xm3.w + q.y * xm2.w + q.z * xm1.w + q.w * x0.w; }
  out.x *= fsigmoid(out.x); out.y *= fsigmoid(out.y);
  out.z *= fsigmoid(out.z); out.w *= fsigmoid(out.w);
  u16x4 ob = {f2bf(out.x), f2bf(out.y), f2bf(out.z), f2bf(out.w)};
  *(u16x4*)((unsigned short*)xscbf + idx) = ob;
}

// ---------- scan pass 1 (state-split 2): per-chunk final state + decay ----------
// Thread layout per wave: lanes 0-31 = states 0-7 (nh=0), lanes 32-63 = states
// 8-15 (nh=1) of the SAME 32 channels. Block = 4 waves = 128 channels.
__global__ __launch_bounds__(256)
void scan_pass1(const __half* __restrict__ dt, const __hip_bfloat16* __restrict__ xsc,
                const float* __restrict__ bc, const float* __restrict__ Aneg,
                float* __restrict__ hfin, float* __restrict__ Pbuf) {
  const int b = blockIdx.z, c = blockIdx.y;
  const int tid = threadIdx.x;
  const int lane = tid & 63;
  const int wv = tid >> 6;
  const int nh = lane >> 5;                         // state half
  const int d = blockIdx.x * 128 + wv * 32 + (lane & 31);
  __shared__ float BC[CLEN][32];
  const size_t mrow0 = (size_t)b * SEQ + (size_t)c * CLEN;
  for (int t = tid; t < CLEN * 32; t += 256) {
    int i = t >> 5, col = t & 31;
    BC[i][col] = bc[(mrow0 + i) * 32 + col];
  }
  __syncthreads();
  float Ar[8];
#pragma unroll
  for (int n = 0; n < 8; ++n) Ar[n] = Aneg[d * 16 + nh * 8 + n];
  float h[8];
#pragma unroll
  for (int n = 0; n < 8; ++n) h[n] = 0.f;
  float dtsum = 0.f;
  size_t base = mrow0 * D_INNER + d;
  for (int l = 0; l < CLEN; ++l) {
    float dtv = __half2float(dt[base + (size_t)l * D_INNER]);
    float u = dtv * bf2f(((const unsigned short*)xsc)[base + (size_t)l * D_INNER]);
    dtsum += dtv;
#pragma unroll
    for (int n = 0; n < 8; ++n) {
      float a = __expf(dtv * Ar[n]);
      h[n] = h[n] * a + u * BC[l][nh * 8 + n];
    }
  }
  size_t o = (((size_t)b * NC + c) * D_INNER + d) * 16 + nh * 8;
#pragma unroll
  for (int n = 0; n < 8; ++n) { hfin[o + n] = h[n]; Pbuf[o + n] = __expf(dtsum * Ar[n]); }
}

// ---------- scan pass 2: cross-chunk combine ----------
__global__ __launch_bounds__(256)
void scan_pass2(float* __restrict__ hfin, const float* __restrict__ Pbuf) {
  int idx = blockIdx.x * 256 + threadIdx.x;  // B*D_INNER*16 = 65536
  int b = idx >> 15;
  int dn = idx & 32767;
  float h0 = 0.f;
  for (int c = 0; c < NC; ++c) {
    size_t o = ((size_t)b * NC + c) * 32768 + dn;
    float hf = hfin[o], p = Pbuf[o];
    hfin[o] = h0;
    h0 = hf + p * h0;
  }
}

// ---------- scan pass 3 (state-split 2): re-run chunk, emit y bf16 ----------
__global__ __launch_bounds__(256)
void scan_pass3(const __half* __restrict__ dt, const __hip_bfloat16* __restrict__ xsc,
                const float* __restrict__ bc, const float* __restrict__ Aneg,
                const float* __restrict__ hinit, const float* __restrict__ Dv,
                const __hip_bfloat16* __restrict__ zsil,
                __hip_bfloat16* __restrict__ ybf) {
  const int b = blockIdx.z, c = blockIdx.y;
  const int tid = threadIdx.x;
  const int lane = tid & 63;
  const int wv = tid >> 6;
  const int nh = lane >> 5;
  const int d = blockIdx.x * 128 + wv * 32 + (lane & 31);
  __shared__ float BC[CLEN][32];
  const size_t mrow0 = (size_t)b * SEQ + (size_t)c * CLEN;
  for (int t = tid; t < CLEN * 32; t += 256) {
    int i = t >> 5, col = t & 31;
    BC[i][col] = bc[(mrow0 + i) * 32 + col];
  }
  __syncthreads();
  float Ar[8];
#pragma unroll
  for (int n = 0; n < 8; ++n) Ar[n] = Aneg[d * 16 + nh * 8 + n];
  float h[8];
  size_t o = (((size_t)b * NC + c) * D_INNER + d) * 16 + nh * 8;
#pragma unroll
  for (int n = 0; n < 8; ++n) h[n] = hinit[o + n];
  const float dval = Dv[d];
  size_t base = mrow0 * D_INNER + d;
  for (int l = 0; l < CLEN; ++l) {
    float dtv = __half2float(dt[base + (size_t)l * D_INNER]);
    float xv = bf2f(((const unsigned short*)xsc)[base + (size_t)l * D_INNER]);
    float u = dtv * xv;
    float y = 0.f;
#pragma unroll
    for (int n = 0; n < 8; ++n) {
      float a = __expf(dtv * Ar[n]);
      h[n] = h[n] * a + u * BC[l][nh * 8 + n];
      y += h[n] * BC[l][16 + nh * 8 + n];
    }
    y += __shfl_xor(y, 32);
    if (nh == 0) {
      float yo = y + xv * dval;
      float zg = __bfloat162float(zsil[base + (size_t)l * D_INNER]);
      ybf[base + (size_t)l * D_INNER] = __float2bfloat16(yo * zg);
    }
  }
}

extern "C" void kernel_launch(void* const* d_in, const int* in_sizes, int n_in,
                              void* d_out, int out_size, void* d_ws, size_t ws_size,
                              hipStream_t stream) {
  const float* x    = (const float*)d_in[0];
  const float* ipw  = (const float*)d_in[1];
  const float* cw   = (const float*)d_in[2];
  const float* cb   = (const float*)d_in[3];
  const float* xpw  = (const float*)d_in[4];
  const float* dtw  = (const float*)d_in[5];
  const float* dtb  = (const float*)d_in[6];
  const float* alog = (const float*)d_in[7];
  const float* Dv   = (const float*)d_in[8];
  const float* opw  = (const float*)d_in[9];
  float* out = (float*)d_out;

  char* w = (char*)d_ws;
  // layout (bytes); aliases: ybf over xbf+wbf (dead after GEMM1);
  // dtbuf over xsbf (dead after conv); hfin/Pbuf in old fp32-xsc region;
  // xdbl8 in tail region (dead before scans)
  __hip_bfloat16* xbf   = (__hip_bfloat16*)(w + 0);          //  8,388,608
  __hip_bfloat16* wbf   = (__hip_bfloat16*)(w + 8388608);    //  8,388,608
  __hip_bfloat16* ybf   = (__hip_bfloat16*)(w + 0);          // 16,777,216 (alias)
  __hip_bfloat16* owbf  = (__hip_bfloat16*)(w + 16777216);   //  4,194,304
  __hip_bfloat16* xpwbf = (__hip_bfloat16*)(w + 20971520);   //    393,216
  __hip_bfloat16* dtwbf = (__hip_bfloat16*)(w + 21364736);   //    262,144
  float* Aneg           = (float*)(w + 21626880);            //    131,072
  __hip_bfloat16* xsbf  = (__hip_bfloat16*)(w + 21757952);   // 16,777,216
  __half* dtbuf         = (__half*)(w + 21757952);           // 16,777,216 (alias)
  __hip_bfloat16* zsil  = (__hip_bfloat16*)(w + 55312384);   // 16,777,216
  float* hfin           = (float*)(w + 72089600);            // 16,777,216 (NC=64)
  float* Pbuf           = (float*)(w + 88866816);            // 16,777,216 (NC=64)
  __hip_bfloat16* xscbf = (__hip_bfloat16*)(w + 105644032);  // 16,777,216
  __hip_bfloat16* dtrbf = (__hip_bfloat16*)(w + 122421248);  //    524,288
  float* bc             = (float*)(w + 122945536);           //    524,288
  float* xdbl8          = (float*)(w + 123469824);           // 12,582,912
  // total: 140,247,040 bytes

  // 1. convert inputs to bf16 (+ A = -exp(A_log))
  {
    const int total = MROWS * D_MODEL + 2 * D_INNER * D_MODEL + 96 * D_INNER +
                      D_INNER * DT_RANK + D_MODEL * D_INNER + D_INNER * NSTATE;
    setup_convert<<<total / (256 * 8), 256, 0, stream>>>(
        x, ipw, xpw, dtw, opw, alog, xbf, wbf, xpwbf, dtwbf, owbf, Aneg);
  }
  // 2. GEMM1 (8-phase 256²): xz = x @ in_proj^T -> xs bf16, silu(z) bf16
  gemm1_8ph<<<dim3(16, 16), 512, 0, stream>>>(xbf, wbf, xsbf, zsil);
  // 3. depthwise conv + silu -> xsc bf16
  conv_silu<<<(MROWS * D_INNER) / (256 * 4), 256, 0, stream>>>(xsbf, cw, cb, xscbf);
  // 4. GEMM2: x_dbl = xsc @ x_proj^T, split-K=8 partials + reduce
  gemm_bt<1, 64><<<dim3(64, 1, KZ2), 256, 0, stream>>>(
      xscbf, xpwbf, MROWS, 96, D_INNER, D_INNER / KZ2,
      xdbl8, nullptr, nullptr);
  xdbl_finish<<<(MROWS * 96) / 256, 256, 0, stream>>>(xdbl8, dtrbf, bc);
  // 5. GEMM3: dt = softplus(dt_r @ dt_proj^T + b) -> fp16
  gemm_bt<2, 64><<<dim3(64, 16), 256, 0, stream>>>(
      dtrbf, dtwbf, MROWS, D_INNER, DT_RANK, DT_RANK,
      nullptr, dtbuf, dtb);
  // 6-8. chunked selective scan (NC=64, state-split 2 -> 2048 blocks/pass)
  scan_pass1<<<dim3(16, NC, 2), 256, 0, stream>>>(dtbuf, xscbf, bc, Aneg, hfin, Pbuf);
  scan_pass2<<<256, 256, 0, stream>>>(hfin, Pbuf);
  scan_pass3<<<dim3(16, NC, 2), 256, 0, stream>>>(dtbuf, xscbf, bc, Aneg, hfin, Dv, zsil, ybf);
  // 9. GEMM4: out = y @ out_proj^T
  gemm_bt<3, 64><<<dim3(64, 8), 256, 0, stream>>>(
      ybf, owbf, MROWS, D_MODEL, D_INNER, D_INNER,
      out, nullptr, nullptr);
}

// Round 8
// 207.870 us; speedup vs baseline: 1.6151x; 1.0440x over previous
//
#include <hip/hip_runtime.h>
#include <hip/hip_bf16.h>
#include <hip/hip_fp16.h>
#include <stdint.h>

typedef __attribute__((ext_vector_type(8))) short s16x8;
typedef __attribute__((ext_vector_type(4))) float f32x4;
typedef __attribute__((ext_vector_type(4))) unsigned short u16x4;

#define D_MODEL 1024
#define D_INNER 2048
#define DT_RANK 64
#define NSTATE 16
#define BATCH 2
#define SEQ 2048
#define MROWS (BATCH*SEQ)   // 4096
#define NC 64
#define CLEN (SEQ/NC)       // 32
#define KZ2 8               // GEMM2 split-K factor

__device__ __forceinline__ float fsigmoid(float v) { return 1.f / (1.f + __expf(-v)); }

__device__ __forceinline__ unsigned short f2bf(float f) {
  __hip_bfloat16 h = __float2bfloat16(f);
  return *(unsigned short*)&h;
}

__device__ __forceinline__ float bf2f(unsigned short u) {
  return __uint_as_float(((unsigned int)u) << 16);
}

__device__ __forceinline__ void gl_lds16(const void* g, void* l) {
  __builtin_amdgcn_global_load_lds(
      (const __attribute__((address_space(1))) void*)g,
      (__attribute__((address_space(3))) void*)l, 16, 0, 0);
}

// ---------- setup: fp32->bf16 conversions + A = -exp(A_log), 8 elems/thread ----------
__global__ __launch_bounds__(256) void setup_convert(
    const float* __restrict__ x, const float* __restrict__ ipw,
    const float* __restrict__ xpw, const float* __restrict__ dtw,
    const float* __restrict__ opw, const float* __restrict__ alog,
    __hip_bfloat16* __restrict__ xbf, __hip_bfloat16* __restrict__ wbf,
    __hip_bfloat16* __restrict__ xpwbf, __hip_bfloat16* __restrict__ dtwbf,
    __hip_bfloat16* __restrict__ owbf, float* __restrict__ Aneg) {
  const int i = (blockIdx.x * 256 + threadIdx.x) * 8;
  const int n0 = MROWS * D_MODEL;               // x
  const int n1 = n0 + 2 * D_INNER * D_MODEL;    // in_proj
  const int n2 = n1 + 96 * D_INNER;             // x_proj
  const int n3 = n2 + D_INNER * DT_RANK;        // dt_proj
  const int n4 = n3 + D_MODEL * D_INNER;        // out_proj
  const int n5 = n4 + D_INNER * NSTATE;         // A_log
  const float* src; __hip_bfloat16* dst; int j;
  if (i < n0)      { src = x;    dst = xbf;   j = i; }
  else if (i < n1) { src = ipw;  dst = wbf;   j = i - n0; }
  else if (i < n2) { src = xpw;  dst = xpwbf; j = i - n1; }
  else if (i < n3) { src = dtw;  dst = dtwbf; j = i - n2; }
  else if (i < n4) { src = opw;  dst = owbf;  j = i - n3; }
  else if (i < n5) {
    int j2 = i - n4;
    float4 a = *(const float4*)(alog + j2);
    float4 b = *(const float4*)(alog + j2 + 4);
    float4 oa = {-expf(a.x), -expf(a.y), -expf(a.z), -expf(a.w)};
    float4 ob = {-expf(b.x), -expf(b.y), -expf(b.z), -expf(b.w)};
    *(float4*)(Aneg + j2) = oa;
    *(float4*)(Aneg + j2 + 4) = ob;
    return;
  } else return;
  float4 a = *(const float4*)(src + j);
  float4 b = *(const float4*)(src + j + 4);
  union { s16x8 v; unsigned short u[8]; } o;
  o.u[0] = f2bf(a.x); o.u[1] = f2bf(a.y); o.u[2] = f2bf(a.z); o.u[3] = f2bf(a.w);
  o.u[4] = f2bf(b.x); o.u[5] = f2bf(b.y); o.u[6] = f2bf(b.z); o.u[7] = f2bf(b.w);
  *(s16x8*)(dst + j) = o.v;
}

// ======================================================================
// GEMM1: 256x256 tile, BK=64, 8 waves (2Mx4N), 8-phase schedule with
// counted vmcnt (T3+T4), (row&7)<<4 LDS XOR-swizzle (T2/G4), setprio (T5).
// Swizzle: physical slot (row, c) holds global (row, c^(row&7)); reads
// access byte = row*128 + (col ^ ((row&7)<<4)). Spreads each frag read
// across all 8 16B-slots -> all 32 banks (row stride 128B is bank-neutral).
// ======================================================================
#define K1 1024
__device__ __forceinline__ void stage_tile1(const __hip_bfloat16* __restrict__ src,
                                            int row0, unsigned short* ldsbase,
                                            int k0, int wave, int lane) {
#pragma unroll
  for (int j = 0; j < 4; ++j) {
    const int s = j * 512 + wave * 64 + lane;          // linear 16B slot
    const int row = s >> 3;
    const int c8 = (s & 7) ^ (row & 7);                // inverse swizzle
    gl_lds16(src + (size_t)(row0 + row) * K1 + k0 + c8 * 8,
             ldsbase + (size_t)(j * 512 + wave * 64) * 8);
  }
}

__global__ __launch_bounds__(512, 2)
void gemm1_8ph(const __hip_bfloat16* __restrict__ A,
               const __hip_bfloat16* __restrict__ Bw,
               __hip_bfloat16* __restrict__ xsbf,
               __hip_bfloat16* __restrict__ zsil) {
  __shared__ unsigned short lds[65536];  // 131072 B
  const int m0 = blockIdx.y * 256;
  const int n0 = blockIdx.x * 256;
  const int tid = threadIdx.x;
  const int lane = tid & 63;
  const int wave = tid >> 6;
  const int wr = wave >> 2;
  const int wc = wave & 3;
  const int lr = lane & 15;
  const int kh = lane >> 4;

  f32x4 acc[8][4] = {};
  s16x8 af[4][2], bfr[4][2];

  const int NT = K1 / 64;  // 16

  stage_tile1(A,  m0, lds, 0, wave, lane);
  stage_tile1(Bw, n0, lds + 16384, 0, wave, lane);
  stage_tile1(A,  m0, lds + 32768, 64, wave, lane);
  stage_tile1(Bw, n0, lds + 32768 + 16384, 64, wave, lane);
  asm volatile("s_waitcnt vmcnt(0)" ::: "memory");
  __builtin_amdgcn_s_barrier();
  __builtin_amdgcn_sched_barrier(0);

  for (int t = 0; t < NT; ++t) {
    const int buf = t & 1;
    const char* abase = (const char*)lds + buf * 65536;
    const char* bbase = abase + 32768;
    const bool st = (t < NT - 2);
    const int k2 = (t + 2) * 64;

    // ---- P1 ----
#pragma unroll
    for (int f = 0; f < 4; ++f) {
      const int row = wr * 128 + f * 16 + lr;
      const int sw = (row & 7) << 4;
#pragma unroll
      for (int ks = 0; ks < 2; ++ks)
        af[f][ks] = *(const s16x8*)(abase + row * 128 + ((ks * 64 + kh * 16) ^ sw));
    }
#pragma unroll
    for (int g = 0; g < 2; ++g) {
      const int row = wc * 64 + g * 16 + lr;
      const int sw = (row & 7) << 4;
#pragma unroll
      for (int ks = 0; ks < 2; ++ks)
        bfr[g][ks] = *(const s16x8*)(bbase + row * 128 + ((ks * 64 + kh * 16) ^ sw));
    }
    __builtin_amdgcn_s_barrier();
    __builtin_amdgcn_sched_barrier(0);
    __builtin_amdgcn_s_setprio(1);
#pragma unroll
    for (int f = 0; f < 4; ++f)
#pragma unroll
      for (int g = 0; g < 2; ++g)
#pragma unroll
        for (int ks = 0; ks < 2; ++ks)
          acc[f][g] = __builtin_amdgcn_mfma_f32_16x16x32_bf16(bfr[g][ks], af[f][ks], acc[f][g], 0, 0, 0);
    __builtin_amdgcn_s_setprio(0);
    __builtin_amdgcn_s_barrier();
    __builtin_amdgcn_sched_barrier(0);

    // ---- P2 ----
#pragma unroll
    for (int g = 2; g < 4; ++g) {
      const int row = wc * 64 + g * 16 + lr;
      const int sw = (row & 7) << 4;
#pragma unroll
      for (int ks = 0; ks < 2; ++ks)
        bfr[g][ks] = *(const s16x8*)(bbase + row * 128 + ((ks * 64 + kh * 16) ^ sw));
    }
    __builtin_amdgcn_s_barrier();
    __builtin_amdgcn_sched_barrier(0);
    __builtin_amdgcn_s_setprio(1);
#pragma unroll
    for (int f = 0; f < 4; ++f)
#pragma unroll
      for (int g = 2; g < 4; ++g)
#pragma unroll
        for (int ks = 0; ks < 2; ++ks)
          acc[f][g] = __builtin_amdgcn_mfma_f32_16x16x32_bf16(bfr[g][ks], af[f][ks], acc[f][g], 0, 0, 0);
    __builtin_amdgcn_s_setprio(0);
    __builtin_amdgcn_s_barrier();
    __builtin_amdgcn_sched_barrier(0);

    // ---- P3 ----
#pragma unroll
    for (int f = 0; f < 4; ++f) {
      const int row = wr * 128 + 64 + f * 16 + lr;
      const int sw = (row & 7) << 4;
#pragma unroll
      for (int ks = 0; ks < 2; ++ks)
        af[f][ks] = *(const s16x8*)(abase + row * 128 + ((ks * 64 + kh * 16) ^ sw));
    }
    if (st) stage_tile1(Bw, n0, lds + buf * 32768 + 16384, k2, wave, lane);
    __builtin_amdgcn_s_barrier();
    __builtin_amdgcn_sched_barrier(0);
    __builtin_amdgcn_s_setprio(1);
#pragma unroll
    for (int f = 0; f < 4; ++f)
#pragma unroll
      for (int g = 0; g < 2; ++g)
#pragma unroll
        for (int ks = 0; ks < 2; ++ks)
          acc[4 + f][g] = __builtin_amdgcn_mfma_f32_16x16x32_bf16(bfr[g][ks], af[f][ks], acc[4 + f][g], 0, 0, 0);
    __builtin_amdgcn_s_setprio(0);
    __builtin_amdgcn_s_barrier();
    __builtin_amdgcn_sched_barrier(0);

    // ---- P4 ----
    if (st) stage_tile1(A, m0, lds + buf * 32768, k2, wave, lane);
    __builtin_amdgcn_s_barrier();
    __builtin_amdgcn_sched_barrier(0);
    __builtin_amdgcn_s_setprio(1);
#pragma unroll
    for (int f = 0; f < 4; ++f)
#pragma unroll
      for (int g = 2; g < 4; ++g)
#pragma unroll
        for (int ks = 0; ks < 2; ++ks)
          acc[4 + f][g] = __builtin_amdgcn_mfma_f32_16x16x32_bf16(bfr[g][ks], af[f][ks], acc[4 + f][g], 0, 0, 0);
    __builtin_amdgcn_s_setprio(0);
    if (t < NT - 2) {
      asm volatile("s_waitcnt vmcnt(8)" ::: "memory");
    } else if (t == NT - 2) {
      asm volatile("s_waitcnt vmcnt(0)" ::: "memory");
    }
    if (t < NT - 1) {
      __builtin_amdgcn_s_barrier();
      __builtin_amdgcn_sched_barrier(0);
    }
  }

  const bool isz = (n0 >= D_INNER);
  unsigned short* outp = (unsigned short*)(isz ? zsil : xsbf);
  const int nc0 = isz ? (n0 - D_INNER) : n0;
#pragma unroll
  for (int mf = 0; mf < 8; ++mf) {
    const int m = m0 + wr * 128 + mf * 16 + lr;
#pragma unroll
    for (int nf = 0; nf < 4; ++nf) {
      const int nb = nc0 + wc * 64 + nf * 16 + (lane >> 4) * 4;
      f32x4 v = acc[mf][nf];
      u16x4 o;
      if (isz) {
#pragma unroll
        for (int j = 0; j < 4; ++j) { float s = v[j] * fsigmoid(v[j]); o[j] = f2bf(s); }
      } else {
#pragma unroll
        for (int j = 0; j < 4; ++j) o[j] = f2bf(v[j]);
      }
      *(u16x4*)(outp + (size_t)m * D_INNER + nb) = o;
    }
  }
}

// ---------- m97-structure bf16 MFMA GEMM (GEMM2/3/4) ----------
template<int MODE, int BM>
__global__ __launch_bounds__(256)
void gemm_bt(const __hip_bfloat16* __restrict__ A,
             const __hip_bfloat16* __restrict__ Bw,
             int M, int N, int K, int kchunk,
             float* __restrict__ e0,
             __half* __restrict__ eh,
             const float* __restrict__ bias) {
  constexpr int FM = BM / 32;
  constexpr int ABUF = BM * 32;
  constexpr int AW = ABUF / 4;
  constexpr int AI = BM / 64;
  __shared__ unsigned short As[2 * ABUF];
  __shared__ unsigned short Bs[2 * 128 * 32];
  const int m0 = blockIdx.x * BM;
  const int n0 = blockIdx.y * 128;
  const int kz = blockIdx.z;
  const int kb = kz * kchunk;
  const int nt = kchunk >> 5;
  const int tid = threadIdx.x;
  const int lane = tid & 63;
  const int wave = tid >> 6;
  const int wr = wave >> 1, wc = wave & 1;
  const int lrow = lane & 15;
  const int kh = lane >> 4;
  const int srow = lane >> 2;
  const int sc8 = (lane & 3) * 8;

  f32x4 acc[FM][4] = {};

  auto STAGE = [&](int buf, int k0) {
#pragma unroll
    for (int i = 0; i < AI; ++i) {
      const int row = wave * (AW / 32) + i * 16 + srow;
      gl_lds16(A + (size_t)(m0 + row) * K + k0 + sc8,
               As + buf * ABUF + wave * AW + i * 512);
    }
#pragma unroll
    for (int i = 0; i < 2; ++i) {
      const int row = wave * 32 + i * 16 + srow;
      int brow = n0 + row; if (brow >= N) brow = N - 1;
      gl_lds16(Bw + (size_t)brow * K + k0 + sc8,
               Bs + buf * 4096 + wave * 1024 + i * 512);
    }
  };

  STAGE(0, kb);
  __syncthreads();

  for (int t = 0; t < nt; ++t) {
    const int cur = t & 1;
    if (t + 1 < nt) STAGE(cur ^ 1, kb + ((t + 1) << 5));
    s16x8 af[FM], bfr[4];
#pragma unroll
    for (int f = 0; f < FM; ++f)
      af[f] = *(const s16x8*)(As + cur * ABUF + (wr * (BM / 2) + f * 16 + lrow) * 32 + kh * 8);
#pragma unroll
    for (int g = 0; g < 4; ++g)
      bfr[g] = *(const s16x8*)(Bs + cur * 4096 + (wc * 64 + g * 16 + lrow) * 32 + kh * 8);
#pragma unroll
    for (int f = 0; f < FM; ++f)
#pragma unroll
      for (int g = 0; g < 4; ++g)
        acc[f][g] = __builtin_amdgcn_mfma_f32_16x16x32_bf16(bfr[g], af[f], acc[f][g], 0, 0, 0);
    if (t + 1 < nt) __syncthreads();
  }

#pragma unroll
  for (int f = 0; f < FM; ++f) {
    const int m = m0 + wr * (BM / 2) + f * 16 + (lane & 15);
#pragma unroll
    for (int g = 0; g < 4; ++g) {
      const int nb = n0 + wc * 64 + g * 16 + (lane >> 4) * 4;
      f32x4 v = acc[f][g];
      if (MODE == 1) {
        if (nb < 96) {
          float4 r = {v[0], v[1], v[2], v[3]};
          *(float4*)(e0 + ((size_t)kz * MROWS + m) * 96 + nb) = r;
        }
      } else if (MODE == 2) {
        float4 bb = *(const float4*)(bias + nb);
        u16x4 o;
        float t0 = v[0] + bb.x; float r0 = (t0 > 20.f) ? t0 : __logf(1.f + __expf(t0));
        float t1 = v[1] + bb.y; float r1 = (t1 > 20.f) ? t1 : __logf(1.f + __expf(t1));
        float t2 = v[2] + bb.z; float r2 = (t2 > 20.f) ? t2 : __logf(1.f + __expf(t2));
        float t3 = v[3] + bb.w; float r3 = (t3 > 20.f) ? t3 : __logf(1.f + __expf(t3));
        o[0] = __half_as_ushort(__float2half(r0));
        o[1] = __half_as_ushort(__float2half(r1));
        o[2] = __half_as_ushort(__float2half(r2));
        o[3] = __half_as_ushort(__float2half(r3));
        *(u16x4*)((unsigned short*)eh + (size_t)m * D_INNER + nb) = o;
      } else {
        float4 r = {v[0], v[1], v[2], v[3]};
        *(float4*)(e0 + (size_t)m * D_MODEL + nb) = r;
      }
    }
  }
}

// ---------- reduce 8 split-K partials -> dt_r (bf16) + B/C (fp32) ----------
__global__ __launch_bounds__(256)
void xdbl_finish(const float* __restrict__ xdbl8, __hip_bfloat16* __restrict__ dtrbf,
                 float* __restrict__ bc) {
  int i = blockIdx.x * 256 + threadIdx.x;  // 4096*96
  int r = i / 96, c = i - r * 96;
  float v = 0.f;
#pragma unroll
  for (int p = 0; p < KZ2; ++p) v += xdbl8[(size_t)p * (MROWS * 96) + i];
  if (c < DT_RANK) dtrbf[r * DT_RANK + c] = __float2bfloat16(v);
  else bc[r * 32 + (c - DT_RANK)] = v;
}

// ---------- depthwise causal conv (k=4) + bias + silu ----------
__global__ __launch_bounds__(256)
void conv_silu(const __hip_bfloat16* __restrict__ xsb, const float* __restrict__ cw,
               const float* __restrict__ cb,
               __hip_bfloat16* __restrict__ xscbf) {
  const int g = blockIdx.x * 256 + threadIdx.x;
  const int idx = g * 4;
  const int l = (idx >> 11) & (SEQ - 1);
  const int d = idx & (D_INNER - 1);
  const unsigned short* p = (const unsigned short*)xsb + idx;
  float4 xm3 = {0.f, 0.f, 0.f, 0.f}, xm2 = xm3, xm1 = xm3, x0;
  {
    u16x4 u = *(const u16x4*)(p);
    x0.x = bf2f(u[0]); x0.y = bf2f(u[1]); x0.z = bf2f(u[2]); x0.w = bf2f(u[3]);
  }
  if (l >= 1) { u16x4 u = *(const u16x4*)(p - 1 * D_INNER);
    xm1.x = bf2f(u[0]); xm1.y = bf2f(u[1]); xm1.z = bf2f(u[2]); xm1.w = bf2f(u[3]); }
  if (l >= 2) { u16x4 u = *(const u16x4*)(p - 2 * D_INNER);
    xm2.x = bf2f(u[0]); xm2.y = bf2f(u[1]); xm2.z = bf2f(u[2]); xm2.w = bf2f(u[3]); }
  if (l >= 3) { u16x4 u = *(const u16x4*)(p - 3 * D_INNER);
    xm3.x = bf2f(u[0]); xm3.y = bf2f(u[1]); xm3.z = bf2f(u[2]); xm3.w = bf2f(u[3]); }
  const float4* cwv = (const float4*)(cw + d * 4);
  float4 cb4 = *(const float4*)(cb + d);
  float4 out;
  { float4 q = cwv[0]; out.x = cb4.x + q.x * xm3.x + q.y * xm2.x + q.z * xm1.x + q.w * x0.x; }
  { float4 q = cwv[1]; out.y = cb4.y + q.x * xm3.y + q.y * xm2.y + q.z * xm1.y + q.w * x0.y; }
  { float4 q = cwv[2]; out.z = cb4.z + q.x * xm3.z + q.y * xm2.z + q.z * xm1.z + q.w * x0.z; }
  { float4 q = cwv[3]; out.w = cb4.w + q.x * xm3.w + q.y * xm2.w + q.z * xm1.w + q.w * x0.w; }
  out.x *= fsigmoid(out.x); out.y *= fsigmoid(out.y);
  out.z *= fsigmoid(out.z); out.w *= fsigmoid(out.w);
  u16x4 ob = {f2bf(out.x), f2bf(out.y), f2bf(out.z), f2bf(out.w)};
  *(u16x4*)((unsigned short*)xscbf + idx) = ob;
}

// ---------- scan pass 1 (state-split 2): per-chunk final state + dt-sum ----------
// P = exp(dtsum*A) is recomputed in pass2 from dtsum (1 float/chan/chunk),
// replacing the 16-float Pbuf write (saves ~33 MB across pass1+pass2).
__global__ __launch_bounds__(256)
void scan_pass1(const __half* __restrict__ dt, const __hip_bfloat16* __restrict__ xsc,
                const float* __restrict__ bc, const float* __restrict__ Aneg,
                float* __restrict__ hfin, float* __restrict__ dts) {
  const int b = blockIdx.z, c = blockIdx.y;
  const int tid = threadIdx.x;
  const int lane = tid & 63;
  const int wv = tid >> 6;
  const int nh = lane >> 5;                         // state half
  const int d = blockIdx.x * 128 + wv * 32 + (lane & 31);
  __shared__ float BC[CLEN][32];
  const size_t mrow0 = (size_t)b * SEQ + (size_t)c * CLEN;
  for (int t = tid; t < CLEN * 32; t += 256) {
    int i = t >> 5, col = t & 31;
    BC[i][col] = bc[(mrow0 + i) * 32 + col];
  }
  __syncthreads();
  float Ar[8];
#pragma unroll
  for (int n = 0; n < 8; ++n) Ar[n] = Aneg[d * 16 + nh * 8 + n];
  float h[8];
#pragma unroll
  for (int n = 0; n < 8; ++n) h[n] = 0.f;
  float dtsum = 0.f;
  size_t base = mrow0 * D_INNER + d;
  for (int l = 0; l < CLEN; ++l) {
    float dtv = __half2float(dt[base + (size_t)l * D_INNER]);
    float u = dtv * bf2f(((const unsigned short*)xsc)[base + (size_t)l * D_INNER]);
    dtsum += dtv;
#pragma unroll
    for (int n = 0; n < 8; ++n) {
      float a = __expf(dtv * Ar[n]);
      h[n] = h[n] * a + u * BC[l][nh * 8 + n];
    }
  }
  size_t o = (((size_t)b * NC + c) * D_INNER + d) * 16 + nh * 8;
#pragma unroll
  for (int n = 0; n < 8; ++n) hfin[o + n] = h[n];
  if (nh == 0) dts[((size_t)b * NC + c) * D_INNER + d] = dtsum;
}

// ---------- scan pass 2: cross-chunk combine (P recomputed from dtsum) ----------
__global__ __launch_bounds__(256)
void scan_pass2(float* __restrict__ hfin, const float* __restrict__ dts,
                const float* __restrict__ Aneg) {
  int idx = blockIdx.x * 256 + threadIdx.x;  // B*D_INNER*16 = 65536
  int b = idx >> 15;
  int dn = idx & 32767;
  int d = dn >> 4, n = dn & 15;
  const float a = Aneg[dn];
  (void)d;
  float h0 = 0.f;
  for (int c = 0; c < NC; ++c) {
    size_t o = ((size_t)b * NC + c) * 32768 + dn;
    float hf = hfin[o];
    float p = __expf(dts[((size_t)b * NC + c) * D_INNER + d] * a);
    hfin[o] = h0;
    h0 = hf + p * h0;
  }
}

// ---------- scan pass 3 (state-split 2): re-run chunk, emit y bf16 ----------
__global__ __launch_bounds__(256)
void scan_pass3(const __half* __restrict__ dt, const __hip_bfloat16* __restrict__ xsc,
                const float* __restrict__ bc, const float* __restrict__ Aneg,
                const float* __restrict__ hinit, const float* __restrict__ Dv,
                const __hip_bfloat16* __restrict__ zsil,
                __hip_bfloat16* __restrict__ ybf) {
  const int b = blockIdx.z, c = blockIdx.y;
  const int tid = threadIdx.x;
  const int lane = tid & 63;
  const int wv = tid >> 6;
  const int nh = lane >> 5;
  const int d = blockIdx.x * 128 + wv * 32 + (lane & 31);
  __shared__ float BC[CLEN][32];
  const size_t mrow0 = (size_t)b * SEQ + (size_t)c * CLEN;
  for (int t = tid; t < CLEN * 32; t += 256) {
    int i = t >> 5, col = t & 31;
    BC[i][col] = bc[(mrow0 + i) * 32 + col];
  }
  __syncthreads();
  float Ar[8];
#pragma unroll
  for (int n = 0; n < 8; ++n) Ar[n] = Aneg[d * 16 + nh * 8 + n];
  float h[8];
  size_t o = (((size_t)b * NC + c) * D_INNER + d) * 16 + nh * 8;
#pragma unroll
  for (int n = 0; n < 8; ++n) h[n] = hinit[o + n];
  const float dval = Dv[d];
  size_t base = mrow0 * D_INNER + d;
  for (int l = 0; l < CLEN; ++l) {
    float dtv = __half2float(dt[base + (size_t)l * D_INNER]);
    float xv = bf2f(((const unsigned short*)xsc)[base + (size_t)l * D_INNER]);
    float u = dtv * xv;
    float y = 0.f;
#pragma unroll
    for (int n = 0; n < 8; ++n) {
      float a = __expf(dtv * Ar[n]);
      h[n] = h[n] * a + u * BC[l][nh * 8 + n];
      y += h[n] * BC[l][16 + nh * 8 + n];
    }
    y += __shfl_xor(y, 32);
    if (nh == 0) {
      float yo = y + xv * dval;
      float zg = __bfloat162float(zsil[base + (size_t)l * D_INNER]);
      ybf[base + (size_t)l * D_INNER] = __float2bfloat16(yo * zg);
    }
  }
}

extern "C" void kernel_launch(void* const* d_in, const int* in_sizes, int n_in,
                              void* d_out, int out_size, void* d_ws, size_t ws_size,
                              hipStream_t stream) {
  const float* x    = (const float*)d_in[0];
  const float* ipw  = (const float*)d_in[1];
  const float* cw   = (const float*)d_in[2];
  const float* cb   = (const float*)d_in[3];
  const float* xpw  = (const float*)d_in[4];
  const float* dtw  = (const float*)d_in[5];
  const float* dtb  = (const float*)d_in[6];
  const float* alog = (const float*)d_in[7];
  const float* Dv   = (const float*)d_in[8];
  const float* opw  = (const float*)d_in[9];
  float* out = (float*)d_out;

  char* w = (char*)d_ws;
  __hip_bfloat16* xbf   = (__hip_bfloat16*)(w + 0);          //  8,388,608
  __hip_bfloat16* wbf   = (__hip_bfloat16*)(w + 8388608);    //  8,388,608
  __hip_bfloat16* ybf   = (__hip_bfloat16*)(w + 0);          // 16,777,216 (alias)
  __hip_bfloat16* owbf  = (__hip_bfloat16*)(w + 16777216);   //  4,194,304
  __hip_bfloat16* xpwbf = (__hip_bfloat16*)(w + 20971520);   //    393,216
  __hip_bfloat16* dtwbf = (__hip_bfloat16*)(w + 21364736);   //    262,144
  float* Aneg           = (float*)(w + 21626880);            //    131,072
  __hip_bfloat16* xsbf  = (__hip_bfloat16*)(w + 21757952);   // 16,777,216
  __half* dtbuf         = (__half*)(w + 21757952);           // 16,777,216 (alias)
  __hip_bfloat16* zsil  = (__hip_bfloat16*)(w + 55312384);   // 16,777,216
  float* hfin           = (float*)(w + 72089600);            // 16,777,216 (NC=64)
  float* dts            = (float*)(w + 88866816);            //  1,048,576 (NC=64)
  __hip_bfloat16* xscbf = (__hip_bfloat16*)(w + 105644032);  // 16,777,216
  __hip_bfloat16* dtrbf = (__hip_bfloat16*)(w + 122421248);  //    524,288
  float* bc             = (float*)(w + 122945536);           //    524,288
  float* xdbl8          = (float*)(w + 123469824);           // 12,582,912
  // total: 140,247,040 bytes

  // 1. convert inputs to bf16 (+ A = -exp(A_log))
  {
    const int total = MROWS * D_MODEL + 2 * D_INNER * D_MODEL + 96 * D_INNER +
                      D_INNER * DT_RANK + D_MODEL * D_INNER + D_INNER * NSTATE;
    setup_convert<<<total / (256 * 8), 256, 0, stream>>>(
        x, ipw, xpw, dtw, opw, alog, xbf, wbf, xpwbf, dtwbf, owbf, Aneg);
  }
  // 2. GEMM1 (8-phase 256²): xz = x @ in_proj^T -> xs bf16, silu(z) bf16
  gemm1_8ph<<<dim3(16, 16), 512, 0, stream>>>(xbf, wbf, xsbf, zsil);
  // 3. depthwise conv + silu -> xsc bf16
  conv_silu<<<(MROWS * D_INNER) / (256 * 4), 256, 0, stream>>>(xsbf, cw, cb, xscbf);
  // 4. GEMM2: x_dbl = xsc @ x_proj^T, split-K=8 partials + reduce
  gemm_bt<1, 64><<<dim3(64, 1, KZ2), 256, 0, stream>>>(
      xscbf, xpwbf, MROWS, 96, D_INNER, D_INNER / KZ2,
      xdbl8, nullptr, nullptr);
  xdbl_finish<<<(MROWS * 96) / 256, 256, 0, stream>>>(xdbl8, dtrbf, bc);
  // 5. GEMM3: dt = softplus(dt_r @ dt_proj^T + b) -> fp16
  gemm_bt<2, 64><<<dim3(64, 16), 256, 0, stream>>>(
      dtrbf, dtwbf, MROWS, D_INNER, DT_RANK, DT_RANK,
      nullptr, dtbuf, dtb);
  // 6-8. chunked selective scan (NC=64, state-split 2 -> 2048 blocks/pass)
  scan_pass1<<<dim3(16, NC, 2), 256, 0, stream>>>(dtbuf, xscbf, bc, Aneg, hfin, dts);
  scan_pass2<<<256, 256, 0, stream>>>(hfin, dts, Aneg);
  scan_pass3<<<dim3(16, NC, 2), 256, 0, stream>>>(dtbuf, xscbf, bc, Aneg, hfin, Dv, zsil, ybf);
  // 9. GEMM4: out = y @ out_proj^T
  gemm_bt<3, 64><<<dim3(64, 8), 256, 0, stream>>>(
      ybf, owbf, MROWS, D_MODEL, D_INNER, D_INNER,
      out, nullptr, nullptr);
}